// Round 1
// baseline (674.876 us; speedup 1.0000x reference)
//
#include <hip/hip_runtime.h>
#include <hip/hip_bf16.h>

#define S_LEN 2048
#define NH 16
#define DHEAD 64
#define DMODEL 1024
#define BATCH 4
#define LDP 56   // padded LDS row (shorts): 112B rows -> 16B aligned, 2-way banks max

typedef __attribute__((ext_vector_type(4))) float f32x4;
typedef __attribute__((ext_vector_type(8))) short bf16x8;
typedef __attribute__((ext_vector_type(4))) short s16x4;
typedef __attribute__((ext_vector_type(4))) float fl4;

static __device__ __forceinline__ short f2bf(float f) {
  unsigned u = __builtin_bit_cast(unsigned, f);
  u += 0x7fffu + ((u >> 16) & 1u);   // RNE
  return (short)(u >> 16);
}

static __device__ __forceinline__ f32x4 mfma16(bf16x8 a, bf16x8 b, f32x4 c) {
  return __builtin_amdgcn_mfma_f32_16x16x32_bf16(a, b, c, 0, 0, 0);
}

// C = A(f32)[8192x1024] * W(f32)[1024x1024] -> bf16, layout [B,H,S,64] (vt_mode=0)
// or transposed [B,H,64,S] (vt_mode=1). scale folded in (Q: 1/8).
__global__ __launch_bounds__(256) void proj_gemm(
    const float* __restrict__ A, const float* __restrict__ W,
    short* __restrict__ Out, float scale, int vt_mode)
{
  __shared__ short As[128][LDP];
  __shared__ short Bs[128][LDP];   // W tile transposed: Bs[n][k]
  const int tid = threadIdx.x;
  const int lane = tid & 63, wid = tid >> 6;
  const int m0 = blockIdx.y * 128, n0 = blockIdx.x * 128;
  const int wm = (wid >> 1) * 64, wn = (wid & 1) * 64;
  const int lr = lane & 15, g = lane >> 4, lk = g << 3;

  f32x4 acc[4][4] = {};

  for (int k0 = 0; k0 < DMODEL; k0 += 32) {
    __syncthreads();
    // stage A 128x32 f32 -> bf16 LDS
#pragma unroll
    for (int i = 0; i < 4; ++i) {
      int f = tid + i * 256;                  // 1024 float4 chunks
      int r = f >> 3, c = (f & 7) << 2;
      fl4 v = *(const fl4*)(A + (size_t)(m0 + r) * DMODEL + k0 + c);
      s16x4 sv;
      sv.x = f2bf(v.x); sv.y = f2bf(v.y); sv.z = f2bf(v.z); sv.w = f2bf(v.w);
      *(s16x4*)&As[r][c] = sv;
    }
    // stage W 32x128 -> transposed Bs[n][k]
#pragma unroll
    for (int i = 0; i < 4; ++i) {
      int f = tid + i * 256;
      int kr = f >> 5, c = (f & 31) << 2;
      fl4 v = *(const fl4*)(W + (size_t)(k0 + kr) * DMODEL + n0 + c);
      Bs[c + 0][kr] = f2bf(v.x);
      Bs[c + 1][kr] = f2bf(v.y);
      Bs[c + 2][kr] = f2bf(v.z);
      Bs[c + 3][kr] = f2bf(v.w);
    }
    __syncthreads();

    bf16x8 af[4], bf[4];
#pragma unroll
    for (int t = 0; t < 4; ++t) {
      af[t] = *(const bf16x8*)&As[wm + t * 16 + lr][lk];
      bf[t] = *(const bf16x8*)&Bs[wn + t * 16 + lr][lk];
    }
#pragma unroll
    for (int mi = 0; mi < 4; ++mi)
#pragma unroll
      for (int ni = 0; ni < 4; ++ni)
        acc[mi][ni] = mfma16(af[mi], bf[ni], acc[mi][ni]);
  }

  if (!vt_mode) {
#pragma unroll
    for (int mi = 0; mi < 4; ++mi)
#pragma unroll
      for (int ni = 0; ni < 4; ++ni) {
        const int n = n0 + wn + ni * 16 + lr;
        const int h = n >> 6, d = n & 63;
#pragma unroll
        for (int r = 0; r < 4; ++r) {
          const int m = m0 + wm + mi * 16 + g * 4 + r;
          const int b = m >> 11, s = m & (S_LEN - 1);
          Out[(((size_t)b * NH + h) * S_LEN + s) * DHEAD + d] =
              f2bf(acc[mi][ni][r] * scale);
        }
      }
  } else {
#pragma unroll
    for (int mi = 0; mi < 4; ++mi) {
      const int mb = m0 + wm + mi * 16 + g * 4;
      const int b = mb >> 11, s = mb & (S_LEN - 1);
#pragma unroll
      for (int ni = 0; ni < 4; ++ni) {
        const int n = n0 + wn + ni * 16 + lr;
        const int h = n >> 6, d = n & 63;
        s16x4 pv;
        pv.x = f2bf(acc[mi][ni][0] * scale);
        pv.y = f2bf(acc[mi][ni][1] * scale);
        pv.z = f2bf(acc[mi][ni][2] * scale);
        pv.w = f2bf(acc[mi][ni][3] * scale);
        *(s16x4*)(Out + (((size_t)b * NH + h) * DHEAD + d) * S_LEN + s) = pv;
      }
    }
  }
}

// causal flash attention; 4 independent waves per block, 32 q-rows each.
// Qp,Kp: [BH][S][64] bf16 (Q pre-scaled). VT: [BH][64][S]. AO: [B][S][1024].
__global__ __launch_bounds__(256) void attn_kernel(
    const short* __restrict__ Qp, const short* __restrict__ Kp,
    const short* __restrict__ VT, short* __restrict__ AO)
{
  __shared__ short Pl[4][32][LDP];   // wave-private P buffers
  const int tid = threadIdx.x, lane = tid & 63, wid = tid >> 6;
  const int lr = lane & 15, g = lane >> 4, lk = g << 3;
  const int bh = blockIdx.y;
  const int q0 = blockIdx.x * 128 + wid * 32;
  const short* Qb = Qp + (size_t)bh * S_LEN * DHEAD;
  const short* Kb = Kp + (size_t)bh * S_LEN * DHEAD;
  const short* Vb = VT + (size_t)bh * DHEAD * S_LEN;

  bf16x8 qf[2][2];
#pragma unroll
  for (int mi = 0; mi < 2; ++mi)
#pragma unroll
    for (int kc = 0; kc < 2; ++kc)
      qf[mi][kc] = *(const bf16x8*)(Qb + (size_t)(q0 + mi * 16 + lr) * DHEAD + kc * 32 + lk);

  f32x4 o[2][4] = {};
  float mrow[2][4], lrow[2][4];
#pragma unroll
  for (int mi = 0; mi < 2; ++mi)
#pragma unroll
    for (int r = 0; r < 4; ++r) { mrow[mi][r] = -1e30f; lrow[mi][r] = 0.f; }

  for (int kv0 = 0; kv0 < q0 + 32; kv0 += 32) {
    f32x4 st[2][2] = {};
#pragma unroll
    for (int nj = 0; nj < 2; ++nj) {
      const size_t krow = (size_t)(kv0 + nj * 16 + lr) * DHEAD;
      bf16x8 kf0 = *(const bf16x8*)(Kb + krow + lk);
      bf16x8 kf1 = *(const bf16x8*)(Kb + krow + 32 + lk);
#pragma unroll
      for (int mi = 0; mi < 2; ++mi) {
        st[mi][nj] = mfma16(qf[mi][0], kf0, st[mi][nj]);
        st[mi][nj] = mfma16(qf[mi][1], kf1, st[mi][nj]);
      }
    }
    if (kv0 >= q0) {   // diagonal tile: elementwise causal mask
#pragma unroll
      for (int mi = 0; mi < 2; ++mi)
#pragma unroll
        for (int nj = 0; nj < 2; ++nj)
#pragma unroll
          for (int r = 0; r < 4; ++r) {
            int q = mi * 16 + g * 4 + r, kv = nj * 16 + lr;
            if (kv > q) st[mi][nj][r] = -1e30f;
          }
    }
#pragma unroll
    for (int mi = 0; mi < 2; ++mi) {
#pragma unroll
      for (int r = 0; r < 4; ++r) {
        float mx = fmaxf(st[mi][0][r], st[mi][1][r]);
        mx = fmaxf(mx, __shfl_xor(mx, 1));
        mx = fmaxf(mx, __shfl_xor(mx, 2));
        mx = fmaxf(mx, __shfl_xor(mx, 4));
        mx = fmaxf(mx, __shfl_xor(mx, 8));
        const float mold = mrow[mi][r];
        const float mnew = fmaxf(mold, mx);
        const float corr = __expf(mold - mnew);
        mrow[mi][r] = mnew;
        const float p0 = __expf(st[mi][0][r] - mnew);
        const float p1 = __expf(st[mi][1][r] - mnew);
        st[mi][0][r] = p0;
        st[mi][1][r] = p1;
        float ps = p0 + p1;
        ps += __shfl_xor(ps, 1);
        ps += __shfl_xor(ps, 2);
        ps += __shfl_xor(ps, 4);
        ps += __shfl_xor(ps, 8);
        lrow[mi][r] = lrow[mi][r] * corr + ps;
#pragma unroll
        for (int nj = 0; nj < 4; ++nj) o[mi][nj][r] *= corr;
      }
    }
    // P -> wave-private LDS (C-layout -> A-frag layout)
#pragma unroll
    for (int mi = 0; mi < 2; ++mi)
#pragma unroll
      for (int nj = 0; nj < 2; ++nj)
#pragma unroll
        for (int r = 0; r < 4; ++r)
          Pl[wid][mi * 16 + g * 4 + r][nj * 16 + lr] = f2bf(st[mi][nj][r]);
    asm volatile("s_waitcnt lgkmcnt(0)" ::: "memory");
    __builtin_amdgcn_sched_barrier(0);
    bf16x8 pf[2];
    pf[0] = *(const bf16x8*)&Pl[wid][lr][lk];
    pf[1] = *(const bf16x8*)&Pl[wid][16 + lr][lk];
#pragma unroll
    for (int nj = 0; nj < 4; ++nj) {
      bf16x8 vf = *(const bf16x8*)(Vb + (size_t)(nj * 16 + lr) * S_LEN + kv0 + lk);
      o[0][nj] = mfma16(pf[0], vf, o[0][nj]);
      o[1][nj] = mfma16(pf[1], vf, o[1][nj]);
    }
  }

  const int b = bh >> 4, h = bh & 15;
#pragma unroll
  for (int mi = 0; mi < 2; ++mi)
#pragma unroll
    for (int r = 0; r < 4; ++r) {
      const float inv = 1.f / lrow[mi][r];
      const int q = q0 + mi * 16 + g * 4 + r;
      short* dst = AO + ((size_t)b * S_LEN + q) * DMODEL + h * DHEAD;
#pragma unroll
      for (int nj = 0; nj < 4; ++nj)
        dst[nj * 16 + lr] = f2bf(o[mi][nj][r] * inv);
    }
}

// Out(f32)[8192x1024] = AO(bf16)[8192x1024] * W(f32)[1024x1024]
__global__ __launch_bounds__(256) void out_gemm(
    const short* __restrict__ A, const float* __restrict__ W, float* __restrict__ Out)
{
  __shared__ short As[128][LDP];
  __shared__ short Bs[128][LDP];
  const int tid = threadIdx.x;
  const int lane = tid & 63, wid = tid >> 6;
  const int m0 = blockIdx.y * 128, n0 = blockIdx.x * 128;
  const int wm = (wid >> 1) * 64, wn = (wid & 1) * 64;
  const int lr = lane & 15, g = lane >> 4, lk = g << 3;

  f32x4 acc[4][4] = {};

  for (int k0 = 0; k0 < DMODEL; k0 += 32) {
    __syncthreads();
#pragma unroll
    for (int i = 0; i < 2; ++i) {
      int f = tid + i * 256;                  // 512 16B chunks
      int r = f >> 2, c = (f & 3) << 3;
      bf16x8 v = *(const bf16x8*)(A + (size_t)(m0 + r) * DMODEL + k0 + c);
      *(bf16x8*)&As[r][c] = v;
    }
#pragma unroll
    for (int i = 0; i < 4; ++i) {
      int f = tid + i * 256;
      int kr = f >> 5, c = (f & 31) << 2;
      fl4 v = *(const fl4*)(W + (size_t)(k0 + kr) * DMODEL + n0 + c);
      Bs[c + 0][kr] = f2bf(v.x);
      Bs[c + 1][kr] = f2bf(v.y);
      Bs[c + 2][kr] = f2bf(v.z);
      Bs[c + 3][kr] = f2bf(v.w);
    }
    __syncthreads();

    bf16x8 af[4], bf[4];
#pragma unroll
    for (int t = 0; t < 4; ++t) {
      af[t] = *(const bf16x8*)&As[wm + t * 16 + lr][lk];
      bf[t] = *(const bf16x8*)&Bs[wn + t * 16 + lr][lk];
    }
#pragma unroll
    for (int mi = 0; mi < 4; ++mi)
#pragma unroll
      for (int ni = 0; ni < 4; ++ni)
        acc[mi][ni] = mfma16(af[mi], bf[ni], acc[mi][ni]);
  }

#pragma unroll
  for (int mi = 0; mi < 4; ++mi)
#pragma unroll
    for (int ni = 0; ni < 4; ++ni) {
      const int n = n0 + wn + ni * 16 + lr;
#pragma unroll
      for (int r = 0; r < 4; ++r) {
        const int m = m0 + wm + mi * 16 + g * 4 + r;
        Out[(size_t)m * DMODEL + n] = acc[mi][ni][r];
      }
    }
}

extern "C" void kernel_launch(void* const* d_in, const int* in_sizes, int n_in,
                              void* d_out, int out_size, void* d_ws, size_t ws_size,
                              hipStream_t stream) {
  const float* query = (const float*)d_in[0];
  const float* key   = (const float*)d_in[1];
  const float* value = (const float*)d_in[2];
  // d_in[3]: causal mask — hardcoded (triu k=1)
  const float* w_q = (const float*)d_in[4];
  const float* w_k = (const float*)d_in[5];
  const float* w_v = (const float*)d_in[6];
  const float* w_o = (const float*)d_in[7];

  const size_t QKV = (size_t)BATCH * NH * S_LEN * DHEAD;  // 8.4M elems
  short* Qp = (short*)d_ws;          // [B,H,S,64] bf16 (scaled 1/8)
  short* Kp = Qp + QKV;              // [B,H,S,64]
  short* Vt = Kp + QKV;              // [B,H,64,S]
  short* AO = Vt + QKV;              // [B,S,1024]

  dim3 blk(256);
  dim3 gg(DMODEL / 128, (BATCH * S_LEN) / 128);   // (8, 64)
  proj_gemm<<<gg, blk, 0, stream>>>(query, w_q, Qp, 0.125f, 0);
  proj_gemm<<<gg, blk, 0, stream>>>(key,   w_k, Kp, 1.0f,   0);
  proj_gemm<<<gg, blk, 0, stream>>>(value, w_v, Vt, 1.0f,   1);
  attn_kernel<<<dim3(S_LEN / 128, BATCH * NH), blk, 0, stream>>>(Qp, Kp, Vt, AO);
  out_gemm<<<gg, blk, 0, stream>>>(AO, w_o, (float*)d_out);
}

// Round 2
// 541.101 us; speedup vs baseline: 1.2472x; 1.2472x over previous
//
#include <hip/hip_runtime.h>
#include <hip/hip_bf16.h>

#define S_LEN 2048
#define NH 16
#define DHEAD 64
#define DMODEL 1024
#define BATCH 4

typedef __attribute__((ext_vector_type(4))) float f32x4;
typedef __attribute__((ext_vector_type(8))) short bf16x8;
typedef __attribute__((ext_vector_type(4))) short s16x4;
typedef __attribute__((ext_vector_type(4))) float fl4;

static __device__ __forceinline__ short f2bf(float f) {
  unsigned u = __builtin_bit_cast(unsigned, f);
  u += 0x7fffu + ((u >> 16) & 1u);   // RNE
  return (short)(u >> 16);
}
static __device__ __forceinline__ f32x4 mfma16(bf16x8 a, bf16x8 b, f32x4 c) {
  return __builtin_amdgcn_mfma_f32_16x16x32_bf16(a, b, c, 0, 0, 0);
}
static __device__ __forceinline__ void gl_lds16(const short* g, short* l) {
  __builtin_amdgcn_global_load_lds(
      (const __attribute__((address_space(1))) unsigned*)g,
      (__attribute__((address_space(3))) unsigned*)l, 16, 0, 0);
}

// f32 -> bf16 elementwise, 8 elems/thread
__global__ __launch_bounds__(256) void cvt_bf16(const float* __restrict__ src,
                                                short* __restrict__ dst) {
  const size_t i = ((size_t)blockIdx.x * 256 + threadIdx.x) * 8;
  fl4 a = *(const fl4*)(src + i);
  fl4 b = *(const fl4*)(src + i + 4);
  bf16x8 o;
  o[0] = f2bf(a.x); o[1] = f2bf(a.y); o[2] = f2bf(a.z); o[3] = f2bf(a.w);
  o[4] = f2bf(b.x); o[5] = f2bf(b.y); o[6] = f2bf(b.z); o[7] = f2bf(b.w);
  *(bf16x8*)(dst + i) = o;
}

// W f32 [1024k][1024n] -> bf16 transposed [1024n][1024k], 64x64 tiles
__global__ __launch_bounds__(256) void transpose_w(
    const float* __restrict__ w0, const float* __restrict__ w1,
    const float* __restrict__ w2, short* __restrict__ o0,
    short* __restrict__ o1, short* __restrict__ o2) {
  const float* W = blockIdx.z == 0 ? w0 : blockIdx.z == 1 ? w1 : w2;
  short* O = blockIdx.z == 0 ? o0 : blockIdx.z == 1 ? o1 : o2;
  __shared__ __align__(16) short T[64][72];
  const int tid = threadIdx.x;
  const int k0 = blockIdx.y * 64, n0 = blockIdx.x * 64;
#pragma unroll
  for (int i = 0; i < 4; ++i) {
    int c = tid + i * 256;
    int kk = c >> 4, nn = (c & 15) << 2;
    fl4 v = *(const fl4*)(W + (size_t)(k0 + kk) * DMODEL + n0 + nn);
    T[nn + 0][kk] = f2bf(v.x);
    T[nn + 1][kk] = f2bf(v.y);
    T[nn + 2][kk] = f2bf(v.z);
    T[nn + 3][kk] = f2bf(v.w);
  }
  __syncthreads();
#pragma unroll
  for (int i = 0; i < 4; ++i) {
    int c = tid + i * 256;
    int nn = c >> 4, kk = (c & 15) << 2;
    *(s16x4*)(O + (size_t)(n0 + nn) * DMODEL + k0 + kk) = *(const s16x4*)&T[nn][kk];
  }
}

// C[8192x1024] = A(bf16)[8192][1024] * B; BPRE: Bt bf16 [n][k]; else Wf f32 [k][n]
// OUT_MODE 0: bf16 [B,H,S,64]*scale; 1: bf16 [B,H,64,S]; 2: f32 [8192][1024]
template <int OUT_MODE, bool BPRE>
__global__ __launch_bounds__(256) void gemm128(
    const short* __restrict__ A, const short* __restrict__ Bt,
    const float* __restrict__ Wf, void* __restrict__ OutP, float scale) {
  __shared__ __align__(16) short As[128 * 32];
  __shared__ __align__(16) short Bs[128 * 32];
  const int tid = threadIdx.x, lane = tid & 63, wid = tid >> 6;
  const int m0 = blockIdx.y * 128, n0 = blockIdx.x * 128;
  const int wm = (wid >> 1) * 64, wn = (wid & 1) * 64;
  const int lr = lane & 15, g = lane >> 4, lk = g << 3;

  f32x4 acc[4][4] = {};

  const int srow = wid * 32 + (lane >> 2);   // +j*16
  const int scol = (lane & 3) * 8;
  short* ldsA = As + wid * 1024 + lane * 8;  // +j*512
  short* ldsB = Bs + wid * 1024 + lane * 8;

  for (int k0 = 0; k0 < DMODEL; k0 += 32) {
    __syncthreads();
    {
      const short* ga = A + (size_t)(m0 + srow) * DMODEL + k0 + scol;
      gl_lds16(ga, ldsA);
      gl_lds16(ga + (size_t)16 * DMODEL, ldsA + 512);
    }
    if (BPRE) {
      const short* gb = Bt + (size_t)(n0 + srow) * DMODEL + k0 + scol;
      gl_lds16(gb, ldsB);
      gl_lds16(gb + (size_t)16 * DMODEL, ldsB + 512);
    } else {
#pragma unroll
      for (int i = 0; i < 4; ++i) {
        int f = tid + i * 256;
        int kr = f >> 5, c = (f & 31) << 2;
        fl4 v = *(const fl4*)(Wf + (size_t)(k0 + kr) * DMODEL + n0 + c);
        Bs[(c + 0) * 32 + kr] = f2bf(v.x);
        Bs[(c + 1) * 32 + kr] = f2bf(v.y);
        Bs[(c + 2) * 32 + kr] = f2bf(v.z);
        Bs[(c + 3) * 32 + kr] = f2bf(v.w);
      }
    }
    __syncthreads();

    bf16x8 af[4], bfr[4];
#pragma unroll
    for (int t = 0; t < 4; ++t) {
      af[t] = *(const bf16x8*)&As[(wm + t * 16 + lr) * 32 + lk];
      bfr[t] = *(const bf16x8*)&Bs[(wn + t * 16 + lr) * 32 + lk];
    }
#pragma unroll
    for (int mi = 0; mi < 4; ++mi)
#pragma unroll
      for (int ni = 0; ni < 4; ++ni)
        acc[mi][ni] = mfma16(af[mi], bfr[ni], acc[mi][ni]);
  }

  if (OUT_MODE == 0) {
    short* Out = (short*)OutP;
#pragma unroll
    for (int mi = 0; mi < 4; ++mi)
#pragma unroll
      for (int ni = 0; ni < 4; ++ni) {
        const int n = n0 + wn + ni * 16 + lr;
        const int h = n >> 6, d = n & 63;
#pragma unroll
        for (int r = 0; r < 4; ++r) {
          const int m = m0 + wm + mi * 16 + g * 4 + r;
          const int b = m >> 11, s = m & (S_LEN - 1);
          Out[(((size_t)b * NH + h) * S_LEN + s) * DHEAD + d] =
              f2bf(acc[mi][ni][r] * scale);
        }
      }
  } else if (OUT_MODE == 1) {
    short* Out = (short*)OutP;
#pragma unroll
    for (int mi = 0; mi < 4; ++mi) {
      const int mb = m0 + wm + mi * 16 + g * 4;
      const int b = mb >> 11, s = mb & (S_LEN - 1);
#pragma unroll
      for (int ni = 0; ni < 4; ++ni) {
        const int n = n0 + wn + ni * 16 + lr;
        const int h = n >> 6, d = n & 63;
        s16x4 pv;
        pv.x = f2bf(acc[mi][ni][0]);
        pv.y = f2bf(acc[mi][ni][1]);
        pv.z = f2bf(acc[mi][ni][2]);
        pv.w = f2bf(acc[mi][ni][3]);
        *(s16x4*)(Out + (((size_t)b * NH + h) * DHEAD + d) * S_LEN + s) = pv;
      }
    }
  } else {
    float* Out = (float*)OutP;
#pragma unroll
    for (int mi = 0; mi < 4; ++mi)
#pragma unroll
      for (int ni = 0; ni < 4; ++ni) {
        const int n = n0 + wn + ni * 16 + lr;
#pragma unroll
        for (int r = 0; r < 4; ++r) {
          const int m = m0 + wm + mi * 16 + g * 4 + r;
          Out[(size_t)m * DMODEL + n] = acc[mi][ni][r];
        }
      }
  }
}

// causal flash attn, KVBLK=64, balanced strip pairing; Q pre-scaled by 0.125*log2e
__global__ __launch_bounds__(256) void attn2(
    const short* __restrict__ Qp, const short* __restrict__ Kp,
    const short* __restrict__ VT, short* __restrict__ AO) {
  __shared__ __align__(16) short Pl[4][32][72];
  const int tid = threadIdx.x, lane = tid & 63, wid = tid >> 6;
  const int lr = lane & 15, g = lane >> 4, lk = g << 3;
  const int bh = blockIdx.y, bx = blockIdx.x;
  // waves 0,1 -> light strips 2bx,2bx+1; waves 2,3 -> heavy strips 62-2bx,63-2bx
  const int strip = (wid < 2) ? (2 * bx + wid) : (62 - 2 * bx + (wid - 2));
  const int q0 = strip * 32;
  const short* Qb = Qp + (size_t)bh * S_LEN * DHEAD;
  const short* Kb = Kp + (size_t)bh * S_LEN * DHEAD;
  const short* Vb = VT + (size_t)bh * DHEAD * S_LEN;

  bf16x8 qf[2][2];
#pragma unroll
  for (int mi = 0; mi < 2; ++mi)
#pragma unroll
    for (int kc = 0; kc < 2; ++kc)
      qf[mi][kc] = *(const bf16x8*)(Qb + (size_t)(q0 + mi * 16 + lr) * DHEAD + kc * 32 + lk);

  f32x4 o[2][4] = {};
  float mrow[2][4], lsum[2][4];
#pragma unroll
  for (int mi = 0; mi < 2; ++mi)
#pragma unroll
    for (int r = 0; r < 4; ++r) { mrow[mi][r] = -1e30f; lsum[mi][r] = 0.f; }

  for (int kv0 = 0; kv0 < q0 + 32; kv0 += 64) {
    f32x4 st[2][4] = {};
#pragma unroll
    for (int nj = 0; nj < 4; ++nj) {
      const short* kp = Kb + (size_t)(kv0 + nj * 16 + lr) * DHEAD;
      bf16x8 kf0 = *(const bf16x8*)(kp + lk);
      bf16x8 kf1 = *(const bf16x8*)(kp + 32 + lk);
      st[0][nj] = mfma16(qf[0][0], kf0, st[0][nj]);
      st[0][nj] = mfma16(qf[0][1], kf1, st[0][nj]);
      st[1][nj] = mfma16(qf[1][0], kf0, st[1][nj]);
      st[1][nj] = mfma16(qf[1][1], kf1, st[1][nj]);
    }
    if (kv0 + 64 > q0) {   // tile touches/passes the diagonal
      const int kvr = kv0 - q0;
#pragma unroll
      for (int mi = 0; mi < 2; ++mi)
#pragma unroll
        for (int nj = 0; nj < 4; ++nj)
#pragma unroll
          for (int r = 0; r < 4; ++r) {
            int q = mi * 16 + (g << 2) + r, kv = kvr + nj * 16 + lr;
            if (kv > q) st[mi][nj][r] = -1e30f;
          }
    }
#pragma unroll
    for (int mi = 0; mi < 2; ++mi)
#pragma unroll
      for (int r = 0; r < 4; ++r) {
        float mx = fmaxf(fmaxf(st[mi][0][r], st[mi][1][r]),
                         fmaxf(st[mi][2][r], st[mi][3][r]));
        mx = fmaxf(mx, __shfl_xor(mx, 1));
        mx = fmaxf(mx, __shfl_xor(mx, 2));
        mx = fmaxf(mx, __shfl_xor(mx, 4));
        mx = fmaxf(mx, __shfl_xor(mx, 8));
        const float mold = mrow[mi][r];
        const float mnew = fmaxf(mold, mx);
        mrow[mi][r] = mnew;
        const float corr = exp2f(mold - mnew);
        float p0 = exp2f(st[mi][0][r] - mnew);
        float p1 = exp2f(st[mi][1][r] - mnew);
        float p2 = exp2f(st[mi][2][r] - mnew);
        float p3 = exp2f(st[mi][3][r] - mnew);
        st[mi][0][r] = p0; st[mi][1][r] = p1; st[mi][2][r] = p2; st[mi][3][r] = p3;
        float ps = (p0 + p1) + (p2 + p3);
        ps += __shfl_xor(ps, 1);
        ps += __shfl_xor(ps, 2);
        ps += __shfl_xor(ps, 4);
        ps += __shfl_xor(ps, 8);
        lsum[mi][r] = lsum[mi][r] * corr + ps;
#pragma unroll
        for (int nd = 0; nd < 4; ++nd) o[mi][nd][r] *= corr;
      }
    // P (C-layout) -> LDS -> A-frag layout
#pragma unroll
    for (int mi = 0; mi < 2; ++mi)
#pragma unroll
      for (int nj = 0; nj < 4; ++nj)
#pragma unroll
        for (int r = 0; r < 4; ++r)
          Pl[wid][mi * 16 + (g << 2) + r][nj * 16 + lr] = f2bf(st[mi][nj][r]);
    asm volatile("s_waitcnt lgkmcnt(0)" ::: "memory");
    __builtin_amdgcn_sched_barrier(0);
    bf16x8 pf[2][2];
#pragma unroll
    for (int mi = 0; mi < 2; ++mi)
#pragma unroll
      for (int kc = 0; kc < 2; ++kc)
        pf[mi][kc] = *(const bf16x8*)&Pl[wid][mi * 16 + lr][kc * 32 + lk];
#pragma unroll
    for (int kc = 0; kc < 2; ++kc)
#pragma unroll
      for (int nd = 0; nd < 4; ++nd) {
        bf16x8 vf = *(const bf16x8*)(Vb + (size_t)(nd * 16 + lr) * S_LEN + kv0 + kc * 32 + lk);
        o[0][nd] = mfma16(pf[0][kc], vf, o[0][nd]);
        o[1][nd] = mfma16(pf[1][kc], vf, o[1][nd]);
      }
  }

  const int b = bh >> 4, h = bh & 15;
#pragma unroll
  for (int mi = 0; mi < 2; ++mi)
#pragma unroll
    for (int r = 0; r < 4; ++r) {
      const float inv = 1.f / lsum[mi][r];
      const int q = q0 + mi * 16 + (g << 2) + r;
      short* dst = AO + ((size_t)b * S_LEN + q) * DMODEL + h * DHEAD;
#pragma unroll
      for (int nd = 0; nd < 4; ++nd)
        dst[nd * 16 + lr] = f2bf(o[mi][nd][r] * inv);
    }
}

extern "C" void kernel_launch(void* const* d_in, const int* in_sizes, int n_in,
                              void* d_out, int out_size, void* d_ws, size_t ws_size,
                              hipStream_t stream) {
  const float* query = (const float*)d_in[0];
  const float* key   = (const float*)d_in[1];
  const float* value = (const float*)d_in[2];
  const float* w_q = (const float*)d_in[4];
  const float* w_k = (const float*)d_in[5];
  const float* w_v = (const float*)d_in[6];
  const float* w_o = (const float*)d_in[7];

  const size_t QKV = (size_t)BATCH * NH * S_LEN * DHEAD;  // 8388608
  short* Qp = (short*)d_ws;
  short* Kp = Qp + QKV;
  short* Vt = Kp + QKV;
  short* AO = Vt + QKV;
  // d_out (33.5 MB f32) is dead until the final GEMM -> use as staging:
  short* qb  = (short*)d_out;        // 16.8 MB activation bf16
  short* Wtq = qb + QKV;             // 3 x 2.1 MB transposed bf16 weights
  short* Wtk = Wtq + (size_t)DMODEL * DMODEL;
  short* Wtv = Wtk + (size_t)DMODEL * DMODEL;

  dim3 blk(256);
  dim3 gg(DMODEL / 128, (BATCH * S_LEN) / 128);   // (8, 64)
  const float qscale = 0.125f * 1.4426950408889634f;  // 1/sqrt(64) * log2(e)

  transpose_w<<<dim3(16, 16, 3), blk, 0, stream>>>(w_q, w_k, w_v, Wtq, Wtk, Wtv);
  cvt_bf16<<<4096, blk, 0, stream>>>(query, qb);
  gemm128<0, true><<<gg, blk, 0, stream>>>(qb, Wtq, nullptr, Qp, qscale);
  cvt_bf16<<<4096, blk, 0, stream>>>(key, qb);
  gemm128<0, true><<<gg, blk, 0, stream>>>(qb, Wtk, nullptr, Kp, 1.0f);
  cvt_bf16<<<4096, blk, 0, stream>>>(value, qb);
  gemm128<1, true><<<gg, blk, 0, stream>>>(qb, Wtv, nullptr, Vt, 1.0f);
  attn2<<<dim3(16, BATCH * NH), blk, 0, stream>>>(Qp, Kp, Vt, AO);
  gemm128<2, false><<<gg, blk, 0, stream>>>(AO, nullptr, w_o, d_out, 1.0f);
}

// Round 3
// 392.547 us; speedup vs baseline: 1.7192x; 1.3784x over previous
//
#include <hip/hip_runtime.h>
#include <hip/hip_bf16.h>

#define S_LEN 2048
#define NH 16
#define DHEAD 64
#define DMODEL 1024
#define BATCH 4

typedef __attribute__((ext_vector_type(4))) float f32x4;
typedef __attribute__((ext_vector_type(8))) short bf16x8;
typedef __attribute__((ext_vector_type(4))) short s16x4;
typedef __attribute__((ext_vector_type(4))) float fl4;

static __device__ __forceinline__ short f2bf(float f) {
  unsigned u = __builtin_bit_cast(unsigned, f);
  u += 0x7fffu + ((u >> 16) & 1u);   // RNE
  return (short)(u >> 16);
}
static __device__ __forceinline__ f32x4 mfma16(bf16x8 a, bf16x8 b, f32x4 c) {
  return __builtin_amdgcn_mfma_f32_16x16x32_bf16(a, b, c, 0, 0, 0);
}
static __device__ __forceinline__ void gl_lds16(const short* g, short* l) {
  __builtin_amdgcn_global_load_lds(
      (const __attribute__((address_space(1))) unsigned*)g,
      (__attribute__((address_space(3))) unsigned*)l, 16, 0, 0);
}

// f32 -> bf16 elementwise, 8 elems/thread
__global__ __launch_bounds__(256) void cvt_bf16(const float* __restrict__ src,
                                                short* __restrict__ dst) {
  const size_t i = ((size_t)blockIdx.x * 256 + threadIdx.x) * 8;
  fl4 a = *(const fl4*)(src + i);
  fl4 b = *(const fl4*)(src + i + 4);
  bf16x8 o;
  o[0] = f2bf(a.x); o[1] = f2bf(a.y); o[2] = f2bf(a.z); o[3] = f2bf(a.w);
  o[4] = f2bf(b.x); o[5] = f2bf(b.y); o[6] = f2bf(b.z); o[7] = f2bf(b.w);
  *(bf16x8*)(dst + i) = o;
}

// W f32 [1024k][1024n] -> bf16 transposed [1024n][1024k], 64x64 tiles
__global__ __launch_bounds__(256) void transpose_w3(
    const float* __restrict__ w0, const float* __restrict__ w1,
    const float* __restrict__ w2, short* __restrict__ o0,
    short* __restrict__ o1, short* __restrict__ o2) {
  const float* W = blockIdx.z == 0 ? w0 : blockIdx.z == 1 ? w1 : w2;
  short* O = blockIdx.z == 0 ? o0 : blockIdx.z == 1 ? o1 : o2;
  __shared__ __align__(16) short T[64][72];
  const int tid = threadIdx.x;
  const int k0 = blockIdx.y * 64, n0 = blockIdx.x * 64;
#pragma unroll
  for (int i = 0; i < 4; ++i) {
    int c = tid + i * 256;
    int kk = c >> 4, nn = (c & 15) << 2;
    fl4 v = *(const fl4*)(W + (size_t)(k0 + kk) * DMODEL + n0 + nn);
    T[nn + 0][kk] = f2bf(v.x);
    T[nn + 1][kk] = f2bf(v.y);
    T[nn + 2][kk] = f2bf(v.z);
    T[nn + 3][kk] = f2bf(v.w);
  }
  __syncthreads();
#pragma unroll
  for (int i = 0; i < 4; ++i) {
    int c = tid + i * 256;
    int nn = c >> 4, kk = (c & 15) << 2;
    *(s16x4*)(O + (size_t)(n0 + nn) * DMODEL + k0 + kk) = *(const s16x4*)&T[nn][kk];
  }
}

__global__ __launch_bounds__(256) void transpose_w1(
    const float* __restrict__ W, short* __restrict__ O) {
  __shared__ __align__(16) short T[64][72];
  const int tid = threadIdx.x;
  const int k0 = blockIdx.y * 64, n0 = blockIdx.x * 64;
#pragma unroll
  for (int i = 0; i < 4; ++i) {
    int c = tid + i * 256;
    int kk = c >> 4, nn = (c & 15) << 2;
    fl4 v = *(const fl4*)(W + (size_t)(k0 + kk) * DMODEL + n0 + nn);
    T[nn + 0][kk] = f2bf(v.x);
    T[nn + 1][kk] = f2bf(v.y);
    T[nn + 2][kk] = f2bf(v.z);
    T[nn + 3][kk] = f2bf(v.w);
  }
  __syncthreads();
#pragma unroll
  for (int i = 0; i < 4; ++i) {
    int c = tid + i * 256;
    int nn = c >> 4, kk = (c & 15) << 2;
    *(s16x4*)(O + (size_t)(n0 + nn) * DMODEL + k0 + kk) = *(const s16x4*)&T[nn][kk];
  }
}

// C[8192x1024] = A(bf16)[8192][1024] * B; BPRE: Bt bf16 [n][k]; else Wf f32 [k][n]
// OUT_MODE 0: bf16 [B,H,S,64]*scale; 1: bf16 [B,H,64,S]; 2: f32 [8192][1024]
template <int OUT_MODE, bool BPRE>
__global__ __launch_bounds__(256) void gemm128(
    const short* __restrict__ A, const short* __restrict__ Bt,
    const float* __restrict__ Wf, void* __restrict__ OutP, float scale) {
  __shared__ __align__(16) short As[128 * 32];
  __shared__ __align__(16) short Bs[128 * 32];
  const int tid = threadIdx.x, lane = tid & 63, wid = tid >> 6;
  const int m0 = blockIdx.y * 128, n0 = blockIdx.x * 128;
  const int wm = (wid >> 1) * 64, wn = (wid & 1) * 64;
  const int lr = lane & 15, g = lane >> 4, lk = g << 3;

  f32x4 acc[4][4] = {};

  const int srow = wid * 32 + (lane >> 2);   // +j*16
  const int scol = (lane & 3) * 8;
  short* ldsA = As + wid * 1024 + lane * 8;  // +j*512
  short* ldsB = Bs + wid * 1024 + lane * 8;

  for (int k0 = 0; k0 < DMODEL; k0 += 32) {
    __syncthreads();
    {
      const short* ga = A + (size_t)(m0 + srow) * DMODEL + k0 + scol;
      gl_lds16(ga, ldsA);
      gl_lds16(ga + (size_t)16 * DMODEL, ldsA + 512);
    }
    if (BPRE) {
      const short* gb = Bt + (size_t)(n0 + srow) * DMODEL + k0 + scol;
      gl_lds16(gb, ldsB);
      gl_lds16(gb + (size_t)16 * DMODEL, ldsB + 512);
    } else {
#pragma unroll
      for (int i = 0; i < 4; ++i) {
        int f = tid + i * 256;
        int kr = f >> 5, c = (f & 31) << 2;
        fl4 v = *(const fl4*)(Wf + (size_t)(k0 + kr) * DMODEL + n0 + c);
        Bs[(c + 0) * 32 + kr] = f2bf(v.x);
        Bs[(c + 1) * 32 + kr] = f2bf(v.y);
        Bs[(c + 2) * 32 + kr] = f2bf(v.z);
        Bs[(c + 3) * 32 + kr] = f2bf(v.w);
      }
    }
    __syncthreads();

    bf16x8 af[4], bfr[4];
#pragma unroll
    for (int t = 0; t < 4; ++t) {
      af[t] = *(const bf16x8*)&As[(wm + t * 16 + lr) * 32 + lk];
      bfr[t] = *(const bf16x8*)&Bs[(wn + t * 16 + lr) * 32 + lk];
    }
#pragma unroll
    for (int mi = 0; mi < 4; ++mi)
#pragma unroll
      for (int ni = 0; ni < 4; ++ni)
        acc[mi][ni] = mfma16(af[mi], bfr[ni], acc[mi][ni]);
  }

  if (OUT_MODE == 0) {
    short* Out = (short*)OutP;
#pragma unroll
    for (int mi = 0; mi < 4; ++mi)
#pragma unroll
      for (int ni = 0; ni < 4; ++ni) {
        const int n = n0 + wn + ni * 16 + lr;
        const int h = n >> 6, d = n & 63;
#pragma unroll
        for (int r = 0; r < 4; ++r) {
          const int m = m0 + wm + mi * 16 + g * 4 + r;
          const int b = m >> 11, s = m & (S_LEN - 1);
          Out[(((size_t)b * NH + h) * S_LEN + s) * DHEAD + d] =
              f2bf(acc[mi][ni][r] * scale);
        }
      }
  } else if (OUT_MODE == 1) {
    short* Out = (short*)OutP;
#pragma unroll
    for (int mi = 0; mi < 4; ++mi) {
      const int mb = m0 + wm + mi * 16 + g * 4;
      const int b = mb >> 11, s = mb & (S_LEN - 1);
#pragma unroll
      for (int ni = 0; ni < 4; ++ni) {
        const int n = n0 + wn + ni * 16 + lr;
        const int h = n >> 6, d = n & 63;
        s16x4 pv;
        pv.x = f2bf(acc[mi][ni][0]);
        pv.y = f2bf(acc[mi][ni][1]);
        pv.z = f2bf(acc[mi][ni][2]);
        pv.w = f2bf(acc[mi][ni][3]);
        *(s16x4*)(Out + (((size_t)b * NH + h) * DHEAD + d) * S_LEN + s) = pv;
      }
    }
  } else {
    float* Out = (float*)OutP;
#pragma unroll
    for (int mi = 0; mi < 4; ++mi)
#pragma unroll
      for (int ni = 0; ni < 4; ++ni) {
        const int n = n0 + wn + ni * 16 + lr;
#pragma unroll
        for (int r = 0; r < 4; ++r) {
          const int m = m0 + wm + mi * 16 + g * 4 + r;
          Out[(size_t)m * DMODEL + n] = acc[mi][ni][r];
        }
      }
  }
}

// causal flash attn, swapped-QK^T softmax, 16-row q strips, pair (t, 127-t)
// per wave -> exactly 33 kv64-tiles each. Q pre-scaled by 0.125*log2e.
// Qp,Kp: [BH][S][64] bf16. VT: [BH][64][S]. AO: [B][S][1024] bf16.
__global__ __launch_bounds__(256) void attn3(
    const short* __restrict__ Qp, const short* __restrict__ Kp,
    const short* __restrict__ VT, short* __restrict__ AO) {
  __shared__ __align__(16) short Pl[4][16][72];
  const int tid = threadIdx.x, lane = tid & 63, wid = tid >> 6;
  const int lr = lane & 15, g = lane >> 4, lk = g << 3;
  const int bh = blockIdx.y;
  const int t = blockIdx.x * 4 + wid;          // 0..63
  const short* Qb = Qp + (size_t)bh * S_LEN * DHEAD;
  const short* Kb = Kp + (size_t)bh * S_LEN * DHEAD;
  const short* Vb = VT + (size_t)bh * DHEAD * S_LEN;
  const int b = bh >> 4, h = bh & 15;
  short* Pw = &Pl[wid][0][0];                  // [16][72]

  for (int sidx = 0; sidx < 2; ++sidx) {
    const int strip = sidx ? (127 - t) : t;
    const int q0 = strip * 16;
    const int qa = q0 + lr;                    // this lane's q row (absolute)

    // Q as B-operand: b[l][i] = Q[q0+lr][32c+8g+i]
    bf16x8 qf[2];
    qf[0] = *(const bf16x8*)(Qb + (size_t)qa * DHEAD + lk);
    qf[1] = *(const bf16x8*)(Qb + (size_t)qa * DHEAD + 32 + lk);

    f32x4 ot[4] = {};        // O^T: ot[nd][r] = O[q=lr col][d=16nd+4g+r]
    float m = -1e30f, l = 0.f;

    for (int kv0 = 0; kv0 < q0 + 16; kv0 += 64) {
      f32x4 st[4] = {};      // st[nj][r]: row kv=kv0+16nj+4g+r, col q=lr
#pragma unroll
      for (int nj = 0; nj < 4; ++nj) {
        const short* kp = Kb + (size_t)(kv0 + nj * 16 + lr) * DHEAD;
        bf16x8 kf0 = *(const bf16x8*)(kp + lk);
        bf16x8 kf1 = *(const bf16x8*)(kp + 32 + lk);
        st[nj] = mfma16(kf0, qf[0], st[nj]);
        st[nj] = mfma16(kf1, qf[1], st[nj]);
      }
      if (kv0 + 64 > q0) {   // tile touches the diagonal
#pragma unroll
        for (int nj = 0; nj < 4; ++nj)
#pragma unroll
          for (int r = 0; r < 4; ++r)
            if (kv0 + nj * 16 + (g << 2) + r > qa) st[nj][r] = -1e30f;
      }
      // in-lane max over the 16 held kv values + 2 shfls across g-groups
      float mx = fmaxf(fmaxf(fmaxf(st[0][0], st[0][1]), fmaxf(st[0][2], st[0][3])),
                       fmaxf(fmaxf(st[1][0], st[1][1]), fmaxf(st[1][2], st[1][3])));
      mx = fmaxf(mx, fmaxf(fmaxf(fmaxf(st[2][0], st[2][1]), fmaxf(st[2][2], st[2][3])),
                           fmaxf(fmaxf(st[3][0], st[3][1]), fmaxf(st[3][2], st[3][3]))));
      mx = fmaxf(mx, __shfl_xor(mx, 16));
      mx = fmaxf(mx, __shfl_xor(mx, 32));
      const float mnew = fmaxf(m, mx);
      const float corr = exp2f(m - mnew);
      m = mnew;
      float ps = 0.f;
#pragma unroll
      for (int nj = 0; nj < 4; ++nj) {
#pragma unroll
        for (int r = 0; r < 4; ++r) {
          const float p = exp2f(st[nj][r] - mnew);
          st[nj][r] = p;
          ps += p;
        }
      }
      ps += __shfl_xor(ps, 16);
      ps += __shfl_xor(ps, 32);
      l = l * corr + ps;
#pragma unroll
      for (int nd = 0; nd < 4; ++nd)
#pragma unroll
        for (int r = 0; r < 4; ++r) ot[nd][r] *= corr;

      // P^T (regs) -> P in LDS: row q=lr, cols kv — packed b64 writes
#pragma unroll
      for (int nj = 0; nj < 4; ++nj) {
        s16x4 pk;
        pk.x = f2bf(st[nj][0]); pk.y = f2bf(st[nj][1]);
        pk.z = f2bf(st[nj][2]); pk.w = f2bf(st[nj][3]);
        *(s16x4*)(Pw + lr * 72 + nj * 16 + (g << 2)) = pk;
      }
      asm volatile("s_waitcnt lgkmcnt(0)" ::: "memory");
      __builtin_amdgcn_sched_barrier(0);
      // B-frag of P^T == A-frag of P: same read pattern
      bf16x8 pf0 = *(const bf16x8*)(Pw + lr * 72 + lk);
      bf16x8 pf1 = *(const bf16x8*)(Pw + lr * 72 + 32 + lk);
      // O^T += V^T * P^T
#pragma unroll
      for (int nd = 0; nd < 4; ++nd) {
        const short* vp = Vb + (size_t)(nd * 16 + lr) * S_LEN + kv0;
        bf16x8 vf0 = *(const bf16x8*)(vp + lk);
        bf16x8 vf1 = *(const bf16x8*)(vp + 32 + lk);
        ot[nd] = mfma16(vf0, pf0, ot[nd]);
        ot[nd] = mfma16(vf1, pf1, ot[nd]);
      }
    }

    const float inv = 1.f / l;
    short* dst = AO + ((size_t)b * S_LEN + qa) * DMODEL + h * DHEAD + (g << 2);
#pragma unroll
    for (int nd = 0; nd < 4; ++nd) {
      s16x4 pv;
      pv.x = f2bf(ot[nd][0] * inv);
      pv.y = f2bf(ot[nd][1] * inv);
      pv.z = f2bf(ot[nd][2] * inv);
      pv.w = f2bf(ot[nd][3] * inv);
      *(s16x4*)(dst + nd * 16) = pv;
    }
  }
}

extern "C" void kernel_launch(void* const* d_in, const int* in_sizes, int n_in,
                              void* d_out, int out_size, void* d_ws, size_t ws_size,
                              hipStream_t stream) {
  const float* query = (const float*)d_in[0];
  const float* key   = (const float*)d_in[1];
  const float* value = (const float*)d_in[2];
  const float* w_q = (const float*)d_in[4];
  const float* w_k = (const float*)d_in[5];
  const float* w_v = (const float*)d_in[6];
  const float* w_o = (const float*)d_in[7];

  const size_t QKV = (size_t)BATCH * NH * S_LEN * DHEAD;  // 8388608
  short* Qp = (short*)d_ws;
  short* Kp = Qp + QKV;
  short* Vt = Kp + QKV;
  short* AO = Vt + QKV;
  short* Wto = Qp;                   // w_o^T bf16, reuses Qp after attn
  // d_out (33.5 MB f32) is dead until the final GEMM -> use as staging:
  short* qb  = (short*)d_out;        // 16.8 MB activation bf16
  short* Wtq = qb + QKV;             // 3 x 2.1 MB transposed bf16 weights
  short* Wtk = Wtq + (size_t)DMODEL * DMODEL;
  short* Wtv = Wtk + (size_t)DMODEL * DMODEL;

  dim3 blk(256);
  dim3 gg(DMODEL / 128, (BATCH * S_LEN) / 128);   // (8, 64)
  const float qscale = 0.125f * 1.4426950408889634f;  // 1/sqrt(64) * log2(e)

  transpose_w3<<<dim3(16, 16, 3), blk, 0, stream>>>(w_q, w_k, w_v, Wtq, Wtk, Wtv);
  cvt_bf16<<<4096, blk, 0, stream>>>(query, qb);
  gemm128<0, true><<<gg, blk, 0, stream>>>(qb, Wtq, nullptr, Qp, qscale);
  cvt_bf16<<<4096, blk, 0, stream>>>(key, qb);
  gemm128<0, true><<<gg, blk, 0, stream>>>(qb, Wtk, nullptr, Kp, 1.0f);
  cvt_bf16<<<4096, blk, 0, stream>>>(value, qb);
  gemm128<1, true><<<gg, blk, 0, stream>>>(qb, Wtv, nullptr, Vt, 1.0f);
  attn3<<<dim3(16, BATCH * NH), blk, 0, stream>>>(Qp, Kp, Vt, AO);
  transpose_w1<<<dim3(16, 16), blk, 0, stream>>>(w_o, Wto);
  gemm128<2, true><<<gg, blk, 0, stream>>>(AO, Wto, nullptr, d_out, 1.0f);
}

// Round 4
// 385.398 us; speedup vs baseline: 1.7511x; 1.0185x over previous
//
#include <hip/hip_runtime.h>
#include <hip/hip_bf16.h>

#define S_LEN 2048
#define NH 16
#define DHEAD 64
#define DMODEL 1024
#define BATCH 4

typedef __attribute__((ext_vector_type(4))) float f32x4;
typedef __attribute__((ext_vector_type(8))) short bf16x8;
typedef __attribute__((ext_vector_type(4))) short s16x4;
typedef __attribute__((ext_vector_type(4))) float fl4;
typedef __attribute__((ext_vector_type(4))) unsigned u32x4;

static __device__ __forceinline__ short f2bf(float f) {
  unsigned u = __builtin_bit_cast(unsigned, f);
  u += 0x7fffu + ((u >> 16) & 1u);   // RNE
  return (short)(u >> 16);
}
static __device__ __forceinline__ f32x4 mfma16(bf16x8 a, bf16x8 b, f32x4 c) {
  return __builtin_amdgcn_mfma_f32_16x16x32_bf16(a, b, c, 0, 0, 0);
}
static __device__ __forceinline__ void gl_lds16(const short* g, short* l) {
  __builtin_amdgcn_global_load_lds(
      (const __attribute__((address_space(1))) unsigned*)g,
      (__attribute__((address_space(3))) unsigned*)l, 16, 0, 0);
}
static __device__ __forceinline__ unsigned cvt_pk_bf16(float lo, float hi) {
  unsigned r;
  asm("v_cvt_pk_bf16_f32 %0, %1, %2" : "=v"(r) : "v"(lo), "v"(hi));
  return r;
}

// f32 -> bf16 elementwise, 8 elems/thread
__global__ __launch_bounds__(256) void cvt_bf16(const float* __restrict__ src,
                                                short* __restrict__ dst) {
  const size_t i = ((size_t)blockIdx.x * 256 + threadIdx.x) * 8;
  fl4 a = *(const fl4*)(src + i);
  fl4 b = *(const fl4*)(src + i + 4);
  bf16x8 o;
  o[0] = f2bf(a.x); o[1] = f2bf(a.y); o[2] = f2bf(a.z); o[3] = f2bf(a.w);
  o[4] = f2bf(b.x); o[5] = f2bf(b.y); o[6] = f2bf(b.z); o[7] = f2bf(b.w);
  *(bf16x8*)(dst + i) = o;
}

// W f32 [1024k][1024n] -> bf16 transposed [1024n][1024k], 64x64 tiles
__global__ __launch_bounds__(256) void transpose_w3(
    const float* __restrict__ w0, const float* __restrict__ w1,
    const float* __restrict__ w2, short* __restrict__ o0,
    short* __restrict__ o1, short* __restrict__ o2) {
  const float* W = blockIdx.z == 0 ? w0 : blockIdx.z == 1 ? w1 : w2;
  short* O = blockIdx.z == 0 ? o0 : blockIdx.z == 1 ? o1 : o2;
  __shared__ __align__(16) short T[64][72];
  const int tid = threadIdx.x;
  const int k0 = blockIdx.y * 64, n0 = blockIdx.x * 64;
#pragma unroll
  for (int i = 0; i < 4; ++i) {
    int c = tid + i * 256;
    int kk = c >> 4, nn = (c & 15) << 2;
    fl4 v = *(const fl4*)(W + (size_t)(k0 + kk) * DMODEL + n0 + nn);
    T[nn + 0][kk] = f2bf(v.x);
    T[nn + 1][kk] = f2bf(v.y);
    T[nn + 2][kk] = f2bf(v.z);
    T[nn + 3][kk] = f2bf(v.w);
  }
  __syncthreads();
#pragma unroll
  for (int i = 0; i < 4; ++i) {
    int c = tid + i * 256;
    int nn = c >> 4, kk = (c & 15) << 2;
    *(s16x4*)(O + (size_t)(n0 + nn) * DMODEL + k0 + kk) = *(const s16x4*)&T[nn][kk];
  }
}

__global__ __launch_bounds__(256) void transpose_w1(
    const float* __restrict__ W, short* __restrict__ O) {
  __shared__ __align__(16) short T[64][72];
  const int tid = threadIdx.x;
  const int k0 = blockIdx.y * 64, n0 = blockIdx.x * 64;
#pragma unroll
  for (int i = 0; i < 4; ++i) {
    int c = tid + i * 256;
    int kk = c >> 4, nn = (c & 15) << 2;
    fl4 v = *(const fl4*)(W + (size_t)(k0 + kk) * DMODEL + n0 + nn);
    T[nn + 0][kk] = f2bf(v.x);
    T[nn + 1][kk] = f2bf(v.y);
    T[nn + 2][kk] = f2bf(v.z);
    T[nn + 3][kk] = f2bf(v.w);
  }
  __syncthreads();
#pragma unroll
  for (int i = 0; i < 4; ++i) {
    int c = tid + i * 256;
    int nn = c >> 4, kk = (c & 15) << 2;
    *(s16x4*)(O + (size_t)(n0 + nn) * DMODEL + k0 + kk) = *(const s16x4*)&T[nn][kk];
  }
}

// C[8192x1024] = A(bf16)[8192][1024] * Bt(bf16)[n][k]
// OUT_MODE 0: bf16 [B,H,S,64]*scale; 1: bf16 [B,H,64,S]; 2: f32 [8192][1024]
template <int OUT_MODE>
__global__ __launch_bounds__(256) void gemm128(
    const short* __restrict__ A, const short* __restrict__ Bt,
    void* __restrict__ OutP, float scale) {
  __shared__ __align__(16) short As[128 * 32];
  __shared__ __align__(16) short Bs[128 * 32];
  const int tid = threadIdx.x, lane = tid & 63, wid = tid >> 6;
  const int m0 = blockIdx.y * 128, n0 = blockIdx.x * 128;
  const int wm = (wid >> 1) * 64, wn = (wid & 1) * 64;
  const int lr = lane & 15, g = lane >> 4, lk = g << 3;

  f32x4 acc[4][4] = {};

  const int srow = wid * 32 + (lane >> 2);
  const int scol = (lane & 3) * 8;
  short* ldsA = As + wid * 1024 + lane * 8;
  short* ldsB = Bs + wid * 1024 + lane * 8;

  for (int k0 = 0; k0 < DMODEL; k0 += 32) {
    __syncthreads();
    {
      const short* ga = A + (size_t)(m0 + srow) * DMODEL + k0 + scol;
      gl_lds16(ga, ldsA);
      gl_lds16(ga + (size_t)16 * DMODEL, ldsA + 512);
      const short* gb = Bt + (size_t)(n0 + srow) * DMODEL + k0 + scol;
      gl_lds16(gb, ldsB);
      gl_lds16(gb + (size_t)16 * DMODEL, ldsB + 512);
    }
    __syncthreads();

    bf16x8 af[4], bfr[4];
#pragma unroll
    for (int t = 0; t < 4; ++t) {
      af[t] = *(const bf16x8*)&As[(wm + t * 16 + lr) * 32 + lk];
      bfr[t] = *(const bf16x8*)&Bs[(wn + t * 16 + lr) * 32 + lk];
    }
#pragma unroll
    for (int mi = 0; mi < 4; ++mi)
#pragma unroll
      for (int ni = 0; ni < 4; ++ni)
        acc[mi][ni] = mfma16(af[mi], bfr[ni], acc[mi][ni]);
  }

  if (OUT_MODE == 0) {
    short* Out = (short*)OutP;
#pragma unroll
    for (int mi = 0; mi < 4; ++mi)
#pragma unroll
      for (int ni = 0; ni < 4; ++ni) {
        const int n = n0 + wn + ni * 16 + lr;
        const int h = n >> 6, d = n & 63;
#pragma unroll
        for (int r = 0; r < 4; ++r) {
          const int m = m0 + wm + mi * 16 + g * 4 + r;
          const int b = m >> 11, s = m & (S_LEN - 1);
          Out[(((size_t)b * NH + h) * S_LEN + s) * DHEAD + d] =
              f2bf(acc[mi][ni][r] * scale);
        }
      }
  } else if (OUT_MODE == 1) {
    short* Out = (short*)OutP;
#pragma unroll
    for (int mi = 0; mi < 4; ++mi) {
      const int mb = m0 + wm + mi * 16 + g * 4;
      const int b = mb >> 11, s = mb & (S_LEN - 1);
#pragma unroll
      for (int ni = 0; ni < 4; ++ni) {
        const int n = n0 + wn + ni * 16 + lr;
        const int h = n >> 6, d = n & 63;
        s16x4 pv;
        pv.x = f2bf(acc[mi][ni][0]);
        pv.y = f2bf(acc[mi][ni][1]);
        pv.z = f2bf(acc[mi][ni][2]);
        pv.w = f2bf(acc[mi][ni][3]);
        *(s16x4*)(Out + (((size_t)b * NH + h) * DHEAD + d) * S_LEN + s) = pv;
      }
    }
  } else {
    float* Out = (float*)OutP;
#pragma unroll
    for (int mi = 0; mi < 4; ++mi)
#pragma unroll
      for (int ni = 0; ni < 4; ++ni) {
        const int n = n0 + wn + ni * 16 + lr;
#pragma unroll
        for (int r = 0; r < 4; ++r) {
          const int m = m0 + wm + mi * 16 + g * 4 + r;
          Out[(size_t)m * DMODEL + n] = acc[mi][ni][r];
        }
      }
  }
}

// causal flash attn, swapped-QK^T, zero-LDS P redistribution via permlane swaps,
// defer-rescale (THR=8 in log2 domain), deferred sum-reduce.
// 16-row q strips, pair (t, 127-t) per wave -> 33 kv64-tiles each.
// Qp,Kp: [BH][S][64] bf16 (Q pre-scaled by 0.125*log2e). VT: [BH][64][S].
__global__ __launch_bounds__(256) void attn4(
    const short* __restrict__ Qp, const short* __restrict__ Kp,
    const short* __restrict__ VT, short* __restrict__ AO) {
  const int tid = threadIdx.x, lane = tid & 63, wid = tid >> 6;
  const int lr = lane & 15, g = lane >> 4, lk = g << 3;
  const int bh = blockIdx.y;
  const int t = blockIdx.x * 4 + wid;          // 0..63
  const short* Qb = Qp + (size_t)bh * S_LEN * DHEAD;
  const short* Kb = Kp + (size_t)bh * S_LEN * DHEAD;
  const short* Vb = VT + (size_t)bh * DHEAD * S_LEN;
  const int b = bh >> 4, h = bh & 15;

  for (int sidx = 0; sidx < 2; ++sidx) {
    const int strip = sidx ? (127 - t) : t;
    const int q0 = strip * 16;
    const int qa = q0 + lr;                    // this lane's q row

    bf16x8 qf[2];
    qf[0] = *(const bf16x8*)(Qb + (size_t)qa * DHEAD + lk);
    qf[1] = *(const bf16x8*)(Qb + (size_t)qa * DHEAD + 32 + lk);

    f32x4 ot[4] = {};        // O^T: ot[nd][r] = O[d=16nd+4g+r][q=lr]
    float m = -1e30f, lsum = 0.f;

    const int ntiles = (q0 + 79) >> 6;
    for (int it = 0; it < ntiles; ++it) {
      const int kv0 = it << 6;
      // ---- K loads + QK^T ----
      const short* kp0 = Kb + ((size_t)(kv0 + lr)) * DHEAD + lk;
      bf16x8 kf[4][2];
#pragma unroll
      for (int nj = 0; nj < 4; ++nj) {
        kf[nj][0] = *(const bf16x8*)(kp0 + (size_t)nj * 16 * DHEAD);
        kf[nj][1] = *(const bf16x8*)(kp0 + (size_t)nj * 16 * DHEAD + 32);
      }
      f32x4 st[4] = {};      // P^T: st[nj][r] = S[kv=kv0+16nj+4g+r][q=lr]
#pragma unroll
      for (int nj = 0; nj < 4; ++nj) {
        st[nj] = mfma16(kf[nj][0], qf[0], st[nj]);
        st[nj] = mfma16(kf[nj][1], qf[1], st[nj]);
      }
      // ---- V loads issue early: latency hides under softmax ----
      bf16x8 vf[4][2];
      const short* vp0 = Vb + (size_t)lr * S_LEN + kv0 + lk;
#pragma unroll
      for (int nd = 0; nd < 4; ++nd) {
        vf[nd][0] = *(const bf16x8*)(vp0 + (size_t)nd * 16 * S_LEN);
        vf[nd][1] = *(const bf16x8*)(vp0 + (size_t)nd * 16 * S_LEN + 32);
      }
      // ---- causal mask (last tile only) ----
      if (it == ntiles - 1) {
#pragma unroll
        for (int nj = 0; nj < 4; ++nj)
#pragma unroll
          for (int r = 0; r < 4; ++r)
            if (kv0 + nj * 16 + (g << 2) + r > qa) st[nj][r] = -1e30f;
      }
      // ---- online softmax with defer-rescale ----
      float mx = fmaxf(fmaxf(fmaxf(st[0][0], st[0][1]), fmaxf(st[0][2], st[0][3])),
                       fmaxf(fmaxf(st[1][0], st[1][1]), fmaxf(st[1][2], st[1][3])));
      mx = fmaxf(mx, fmaxf(fmaxf(fmaxf(st[2][0], st[2][1]), fmaxf(st[2][2], st[2][3])),
                           fmaxf(fmaxf(st[3][0], st[3][1]), fmaxf(st[3][2], st[3][3]))));
      mx = fmaxf(mx, __shfl_xor(mx, 16));
      mx = fmaxf(mx, __shfl_xor(mx, 32));
      if (__any(mx > m + 8.0f)) {
        const float mnew = fmaxf(m, mx);
        const float corr = exp2f(m - mnew);
        m = mnew;
        lsum *= corr;
#pragma unroll
        for (int nd = 0; nd < 4; ++nd)
#pragma unroll
          for (int r = 0; r < 4; ++r) ot[nd][r] *= corr;
      }
      float ps = 0.f;
#pragma unroll
      for (int nj = 0; nj < 4; ++nj)
#pragma unroll
        for (int r = 0; r < 4; ++r) {
          const float p = exp2f(st[nj][r] - m);
          st[nj][r] = p;
          ps += p;
        }
      lsum += ps;             // per-lane partial; reduced in epilogue
      // ---- P^T -> B-frag via cvt_pk + permlane swaps (zero LDS) ----
      unsigned pw[2][4];
#pragma unroll
      for (int kc = 0; kc < 2; ++kc)
#pragma unroll
        for (int jj = 0; jj < 2; ++jj) {
          unsigned a = cvt_pk_bf16(st[2 * kc][2 * jj], st[2 * kc][2 * jj + 1]);
          unsigned bb = cvt_pk_bf16(st[2 * kc + 1][2 * jj], st[2 * kc + 1][2 * jj + 1]);
          asm("v_permlane32_swap_b32 %0, %1" : "+v"(a), "+v"(bb));
          asm("v_permlane16_swap_b32 %0, %1" : "+v"(a), "+v"(bb));
          pw[kc][jj] = a;
          pw[kc][jj + 2] = bb;
        }
      u32x4 w0 = {pw[0][0], pw[0][1], pw[0][2], pw[0][3]};
      u32x4 w1 = {pw[1][0], pw[1][1], pw[1][2], pw[1][3]};
      bf16x8 pf0 = __builtin_bit_cast(bf16x8, w0);
      bf16x8 pf1 = __builtin_bit_cast(bf16x8, w1);
      // ---- O^T += V^T * P^T ----
#pragma unroll
      for (int nd = 0; nd < 4; ++nd) {
        ot[nd] = mfma16(vf[nd][0], pf0, ot[nd]);
        ot[nd] = mfma16(vf[nd][1], pf1, ot[nd]);
      }
    }

    lsum += __shfl_xor(lsum, 16);
    lsum += __shfl_xor(lsum, 32);
    const float inv = 1.f / lsum;
    short* dst = AO + ((size_t)b * S_LEN + qa) * DMODEL + h * DHEAD + (g << 2);
#pragma unroll
    for (int nd = 0; nd < 4; ++nd) {
      s16x4 pv;
      pv.x = f2bf(ot[nd][0] * inv);
      pv.y = f2bf(ot[nd][1] * inv);
      pv.z = f2bf(ot[nd][2] * inv);
      pv.w = f2bf(ot[nd][3] * inv);
      *(s16x4*)(dst + nd * 16) = pv;
    }
  }
}

extern "C" void kernel_launch(void* const* d_in, const int* in_sizes, int n_in,
                              void* d_out, int out_size, void* d_ws, size_t ws_size,
                              hipStream_t stream) {
  const float* query = (const float*)d_in[0];
  const float* key   = (const float*)d_in[1];
  const float* value = (const float*)d_in[2];
  const float* w_q = (const float*)d_in[4];
  const float* w_k = (const float*)d_in[5];
  const float* w_v = (const float*)d_in[6];
  const float* w_o = (const float*)d_in[7];

  const size_t QKV = (size_t)BATCH * NH * S_LEN * DHEAD;  // 8388608
  short* Qp = (short*)d_ws;
  short* Kp = Qp + QKV;
  short* Vt = Kp + QKV;
  short* AO = Vt + QKV;
  short* Wto = Qp;                   // w_o^T bf16, reuses Qp after attn
  short* qb  = (short*)d_out;        // d_out as staging until final GEMM
  short* Wtq = qb + QKV;
  short* Wtk = Wtq + (size_t)DMODEL * DMODEL;
  short* Wtv = Wtk + (size_t)DMODEL * DMODEL;

  dim3 blk(256);
  dim3 gg(DMODEL / 128, (BATCH * S_LEN) / 128);   // (8, 64)
  const float qscale = 0.125f * 1.4426950408889634f;  // 1/sqrt(64) * log2(e)

  transpose_w3<<<dim3(16, 16, 3), blk, 0, stream>>>(w_q, w_k, w_v, Wtq, Wtk, Wtv);
  cvt_bf16<<<4096, blk, 0, stream>>>(query, qb);
  gemm128<0><<<gg, blk, 0, stream>>>(qb, Wtq, Qp, qscale);
  cvt_bf16<<<4096, blk, 0, stream>>>(key, qb);
  gemm128<0><<<gg, blk, 0, stream>>>(qb, Wtk, Kp, 1.0f);
  cvt_bf16<<<4096, blk, 0, stream>>>(value, qb);
  gemm128<1><<<gg, blk, 0, stream>>>(qb, Wtv, Vt, 1.0f);
  attn4<<<dim3(16, BATCH * NH), blk, 0, stream>>>(Qp, Kp, Vt, AO);
  transpose_w1<<<dim3(16, 16), blk, 0, stream>>>(w_o, Wto);
  gemm128<2><<<gg, blk, 0, stream>>>(AO, Wto, d_out, 1.0f);
}

// Round 5
// 364.948 us; speedup vs baseline: 1.8492x; 1.0560x over previous
//
#include <hip/hip_runtime.h>
#include <hip/hip_bf16.h>

#define S_LEN 2048
#define NH 16
#define DHEAD 64
#define DMODEL 1024
#define BATCH 4

typedef __attribute__((ext_vector_type(4))) float f32x4;
typedef __attribute__((ext_vector_type(8))) short bf16x8;
typedef __attribute__((ext_vector_type(4))) short s16x4;
typedef __attribute__((ext_vector_type(4))) float fl4;
typedef __attribute__((ext_vector_type(4))) unsigned u32x4;

static __device__ __forceinline__ short f2bf(float f) {
  unsigned u = __builtin_bit_cast(unsigned, f);
  u += 0x7fffu + ((u >> 16) & 1u);   // RNE
  return (short)(u >> 16);
}
static __device__ __forceinline__ f32x4 mfma16(bf16x8 a, bf16x8 b, f32x4 c) {
  return __builtin_amdgcn_mfma_f32_16x16x32_bf16(a, b, c, 0, 0, 0);
}
static __device__ __forceinline__ void gl_lds16(const short* g, short* l) {
  __builtin_amdgcn_global_load_lds(
      (const __attribute__((address_space(1))) unsigned*)g,
      (__attribute__((address_space(3))) unsigned*)l, 16, 0, 0);
}
static __device__ __forceinline__ unsigned cvt_pk_bf16(float lo, float hi) {
  unsigned r;
  asm("v_cvt_pk_bf16_f32 %0, %1, %2" : "=v"(r) : "v"(lo), "v"(hi));
  return r;
}

// f32 -> bf16 elementwise, 8 elems/thread
__global__ __launch_bounds__(256) void cvt_bf16(const float* __restrict__ src,
                                                short* __restrict__ dst) {
  const size_t i = ((size_t)blockIdx.x * 256 + threadIdx.x) * 8;
  fl4 a = *(const fl4*)(src + i);
  fl4 b = *(const fl4*)(src + i + 4);
  bf16x8 o;
  o[0] = f2bf(a.x); o[1] = f2bf(a.y); o[2] = f2bf(a.z); o[3] = f2bf(a.w);
  o[4] = f2bf(b.x); o[5] = f2bf(b.y); o[6] = f2bf(b.z); o[7] = f2bf(b.w);
  *(bf16x8*)(dst + i) = o;
}

// W f32 [1024k][1024n] -> bf16 transposed [1024n][1024k], 64x64 tiles
__global__ __launch_bounds__(256) void transpose_w3(
    const float* __restrict__ w0, const float* __restrict__ w1,
    const float* __restrict__ w2, short* __restrict__ o0,
    short* __restrict__ o1, short* __restrict__ o2) {
  const float* W = blockIdx.z == 0 ? w0 : blockIdx.z == 1 ? w1 : w2;
  short* O = blockIdx.z == 0 ? o0 : blockIdx.z == 1 ? o1 : o2;
  __shared__ __align__(16) short T[64][72];
  const int tid = threadIdx.x;
  const int k0 = blockIdx.y * 64, n0 = blockIdx.x * 64;
#pragma unroll
  for (int i = 0; i < 4; ++i) {
    int c = tid + i * 256;
    int kk = c >> 4, nn = (c & 15) << 2;
    fl4 v = *(const fl4*)(W + (size_t)(k0 + kk) * DMODEL + n0 + nn);
    T[nn + 0][kk] = f2bf(v.x);
    T[nn + 1][kk] = f2bf(v.y);
    T[nn + 2][kk] = f2bf(v.z);
    T[nn + 3][kk] = f2bf(v.w);
  }
  __syncthreads();
#pragma unroll
  for (int i = 0; i < 4; ++i) {
    int c = tid + i * 256;
    int nn = c >> 4, kk = (c & 15) << 2;
    *(s16x4*)(O + (size_t)(n0 + nn) * DMODEL + k0 + kk) = *(const s16x4*)&T[nn][kk];
  }
}

__global__ __launch_bounds__(256) void transpose_w1(
    const float* __restrict__ W, short* __restrict__ O) {
  __shared__ __align__(16) short T[64][72];
  const int tid = threadIdx.x;
  const int k0 = blockIdx.y * 64, n0 = blockIdx.x * 64;
#pragma unroll
  for (int i = 0; i < 4; ++i) {
    int c = tid + i * 256;
    int kk = c >> 4, nn = (c & 15) << 2;
    fl4 v = *(const fl4*)(W + (size_t)(k0 + kk) * DMODEL + n0 + nn);
    T[nn + 0][kk] = f2bf(v.x);
    T[nn + 1][kk] = f2bf(v.y);
    T[nn + 2][kk] = f2bf(v.z);
    T[nn + 3][kk] = f2bf(v.w);
  }
  __syncthreads();
#pragma unroll
  for (int i = 0; i < 4; ++i) {
    int c = tid + i * 256;
    int nn = c >> 4, kk = (c & 15) << 2;
    *(s16x4*)(O + (size_t)(n0 + nn) * DMODEL + k0 + kk) = *(const s16x4*)&T[nn][kk];
  }
}

// C[8192x1024] = A(bf16)[8192][1024] * Bt(bf16)[n][k]
// OUT_MODE 0: bf16 [B,H,S,64]*scale; 1: bf16 [B,H,64,S]; 2: f32 [8192][1024]
template <int OUT_MODE>
__global__ __launch_bounds__(256) void gemm128(
    const short* __restrict__ A, const short* __restrict__ Bt,
    void* __restrict__ OutP, float scale) {
  __shared__ __align__(16) short As[128 * 32];
  __shared__ __align__(16) short Bs[128 * 32];
  const int tid = threadIdx.x, lane = tid & 63, wid = tid >> 6;
  const int m0 = blockIdx.y * 128, n0 = blockIdx.x * 128;
  const int wm = (wid >> 1) * 64, wn = (wid & 1) * 64;
  const int lr = lane & 15, g = lane >> 4, lk = g << 3;

  f32x4 acc[4][4] = {};

  const int srow = wid * 32 + (lane >> 2);
  const int scol = (lane & 3) * 8;
  short* ldsA = As + wid * 1024 + lane * 8;
  short* ldsB = Bs + wid * 1024 + lane * 8;

  for (int k0 = 0; k0 < DMODEL; k0 += 32) {
    __syncthreads();
    {
      const short* ga = A + (size_t)(m0 + srow) * DMODEL + k0 + scol;
      gl_lds16(ga, ldsA);
      gl_lds16(ga + (size_t)16 * DMODEL, ldsA + 512);
      const short* gb = Bt + (size_t)(n0 + srow) * DMODEL + k0 + scol;
      gl_lds16(gb, ldsB);
      gl_lds16(gb + (size_t)16 * DMODEL, ldsB + 512);
    }
    __syncthreads();

    bf16x8 af[4], bfr[4];
#pragma unroll
    for (int t = 0; t < 4; ++t) {
      af[t] = *(const bf16x8*)&As[(wm + t * 16 + lr) * 32 + lk];
      bfr[t] = *(const bf16x8*)&Bs[(wn + t * 16 + lr) * 32 + lk];
    }
#pragma unroll
    for (int mi = 0; mi < 4; ++mi)
#pragma unroll
      for (int ni = 0; ni < 4; ++ni)
        acc[mi][ni] = mfma16(af[mi], bfr[ni], acc[mi][ni]);
  }

  if (OUT_MODE == 0) {
    short* Out = (short*)OutP;
#pragma unroll
    for (int mi = 0; mi < 4; ++mi)
#pragma unroll
      for (int ni = 0; ni < 4; ++ni) {
        const int n = n0 + wn + ni * 16 + lr;
        const int h = n >> 6, d = n & 63;
#pragma unroll
        for (int r = 0; r < 4; ++r) {
          const int m = m0 + wm + mi * 16 + g * 4 + r;
          const int b = m >> 11, s = m & (S_LEN - 1);
          Out[(((size_t)b * NH + h) * S_LEN + s) * DHEAD + d] =
              f2bf(acc[mi][ni][r] * scale);
        }
      }
  } else if (OUT_MODE == 1) {
    short* Out = (short*)OutP;
#pragma unroll
    for (int mi = 0; mi < 4; ++mi) {
      const int mb = m0 + wm + mi * 16 + g * 4;
      const int b = mb >> 11, s = mb & (S_LEN - 1);
#pragma unroll
      for (int ni = 0; ni < 4; ++ni) {
        const int n = n0 + wn + ni * 16 + lr;
        const int h = n >> 6, d = n & 63;
        s16x4 pv;
        pv.x = f2bf(acc[mi][ni][0]);
        pv.y = f2bf(acc[mi][ni][1]);
        pv.z = f2bf(acc[mi][ni][2]);
        pv.w = f2bf(acc[mi][ni][3]);
        *(s16x4*)(Out + (((size_t)b * NH + h) * DHEAD + d) * S_LEN + s) = pv;
      }
    }
  } else {
    float* Out = (float*)OutP;
#pragma unroll
    for (int mi = 0; mi < 4; ++mi)
#pragma unroll
      for (int ni = 0; ni < 4; ++ni) {
        const int n = n0 + wn + ni * 16 + lr;
#pragma unroll
        for (int r = 0; r < 4; ++r) {
          const int m = m0 + wm + mi * 16 + g * 4 + r;
          Out[(size_t)m * DMODEL + n] = acc[mi][ni][r];
        }
      }
  }
}

// ---- attn helpers (swapped-QK^T layout) ----
static __device__ __forceinline__ void softmax_pv(
    f32x4 (&st)[4], f32x4 (&ot)[4], float& m, float& lsum,
    const bf16x8 (&vf)[4][2]) {
  float mx = fmaxf(fmaxf(fmaxf(st[0][0], st[0][1]), fmaxf(st[0][2], st[0][3])),
                   fmaxf(fmaxf(st[1][0], st[1][1]), fmaxf(st[1][2], st[1][3])));
  mx = fmaxf(mx, fmaxf(fmaxf(fmaxf(st[2][0], st[2][1]), fmaxf(st[2][2], st[2][3])),
                       fmaxf(fmaxf(st[3][0], st[3][1]), fmaxf(st[3][2], st[3][3]))));
  mx = fmaxf(mx, __shfl_xor(mx, 16));
  mx = fmaxf(mx, __shfl_xor(mx, 32));
  if (__any(mx > m + 8.0f)) {          // defer-rescale (log2 domain)
    const float mnew = fmaxf(m, mx);
    const float corr = exp2f(m - mnew);
    m = mnew;
    lsum *= corr;
#pragma unroll
    for (int nd = 0; nd < 4; ++nd)
#pragma unroll
      for (int r = 0; r < 4; ++r) ot[nd][r] *= corr;
  }
  float ps = 0.f;
#pragma unroll
  for (int nj = 0; nj < 4; ++nj)
#pragma unroll
    for (int r = 0; r < 4; ++r) {
      const float p = exp2f(st[nj][r] - m);
      st[nj][r] = p;
      ps += p;
    }
  lsum += ps;                           // per-lane partial
  // P^T -> B-frag via cvt_pk + permlane swaps (zero LDS)
  unsigned pw[2][4];
#pragma unroll
  for (int kc = 0; kc < 2; ++kc)
#pragma unroll
    for (int jj = 0; jj < 2; ++jj) {
      unsigned a = cvt_pk_bf16(st[2 * kc][2 * jj], st[2 * kc][2 * jj + 1]);
      unsigned bb = cvt_pk_bf16(st[2 * kc + 1][2 * jj], st[2 * kc + 1][2 * jj + 1]);
      asm("v_permlane32_swap_b32 %0, %1" : "+v"(a), "+v"(bb));
      asm("v_permlane16_swap_b32 %0, %1" : "+v"(a), "+v"(bb));
      pw[kc][jj] = a;
      pw[kc][jj + 2] = bb;
    }
  u32x4 w0 = {pw[0][0], pw[0][1], pw[0][2], pw[0][3]};
  u32x4 w1 = {pw[1][0], pw[1][1], pw[1][2], pw[1][3]};
  bf16x8 pf0 = __builtin_bit_cast(bf16x8, w0);
  bf16x8 pf1 = __builtin_bit_cast(bf16x8, w1);
#pragma unroll
  for (int nd = 0; nd < 4; ++nd) {
    ot[nd] = mfma16(vf[nd][0], pf0, ot[nd]);
    ot[nd] = mfma16(vf[nd][1], pf1, ot[nd]);
  }
}

static __device__ __forceinline__ void attn_epilogue(
    f32x4 (&ot)[4], float lsum, int b, int h, int qa, int g,
    short* __restrict__ AO) {
  lsum += __shfl_xor(lsum, 16);
  lsum += __shfl_xor(lsum, 32);
  const float inv = 1.f / lsum;
  short* dst = AO + ((size_t)b * S_LEN + qa) * DMODEL + h * DHEAD + (g << 2);
#pragma unroll
  for (int nd = 0; nd < 4; ++nd) {
    s16x4 pv;
    pv.x = f2bf(ot[nd][0] * inv);
    pv.y = f2bf(ot[nd][1] * inv);
    pv.z = f2bf(ot[nd][2] * inv);
    pv.w = f2bf(ot[nd][3] * inv);
    *(s16x4*)(dst + nd * 16) = pv;
  }
}

// causal flash attn, swapped QK^T, XCD-local bh, strip pair (t, 127-t)
// processed in ONE interleaved kv loop (shared K/V tile loads).
// Qp,Kp: [BH][S][64] bf16 (Q pre-scaled by 0.125*log2e). VT: [BH][64][S].
__global__ __launch_bounds__(256) void attn5(
    const short* __restrict__ Qp, const short* __restrict__ Kp,
    const short* __restrict__ VT, short* __restrict__ AO) {
  const int tid = threadIdx.x, lane = tid & 63, wid = tid >> 6;
  const int lr = lane & 15, g = lane >> 4, lk = g << 3;
  // XCD swizzle: id%8 = XCD; each XCD owns bh in [8*xcd, 8*xcd+8)
  const int id = blockIdx.x;
  const int xcd = id & 7, lid = id >> 3;       // lid 0..127
  const int bh = xcd * 8 + (lid >> 4);
  const int bx = lid & 15;
  const int t = bx * 4 + wid;                  // 0..63
  const short* Qb = Qp + (size_t)bh * S_LEN * DHEAD;
  const short* Kb = Kp + (size_t)bh * S_LEN * DHEAD;
  const short* Vb = VT + (size_t)bh * DHEAD * S_LEN;
  const int b = bh >> 4, h = bh & 15;

  const int q0A = t << 4, q0B = (127 - t) << 4;
  const int qaA = q0A + lr, qaB = q0B + lr;
  const int ntA = (q0A + 79) >> 6, ntB = (q0B + 79) >> 6;   // ntA+ntB == 33

  bf16x8 qfA[2], qfB[2];
  qfA[0] = *(const bf16x8*)(Qb + (size_t)qaA * DHEAD + lk);
  qfA[1] = *(const bf16x8*)(Qb + (size_t)qaA * DHEAD + 32 + lk);
  qfB[0] = *(const bf16x8*)(Qb + (size_t)qaB * DHEAD + lk);
  qfB[1] = *(const bf16x8*)(Qb + (size_t)qaB * DHEAD + 32 + lk);

  f32x4 otA[4] = {}, otB[4] = {};
  float mA = -1e30f, lA = 0.f, mB = -1e30f, lB = 0.f;

  for (int it = 0; it < ntB; ++it) {
    const int kv0 = it << 6;
    // ---- K tile loads ----
    const short* kp0 = Kb + ((size_t)(kv0 + lr)) * DHEAD + lk;
    bf16x8 kf[4][2];
#pragma unroll
    for (int nj = 0; nj < 4; ++nj) {
      kf[nj][0] = *(const bf16x8*)(kp0 + (size_t)nj * 16 * DHEAD);
      kf[nj][1] = *(const bf16x8*)(kp0 + (size_t)nj * 16 * DHEAD + 32);
    }
    const bool doA = (it < ntA);
    // ---- QK^T for both strips off the same K tile ----
    f32x4 stA[4] = {}, stB[4] = {};
#pragma unroll
    for (int nj = 0; nj < 4; ++nj) {
      stB[nj] = mfma16(kf[nj][0], qfB[0], stB[nj]);
      stB[nj] = mfma16(kf[nj][1], qfB[1], stB[nj]);
    }
    if (doA) {
#pragma unroll
      for (int nj = 0; nj < 4; ++nj) {
        stA[nj] = mfma16(kf[nj][0], qfA[0], stA[nj]);
        stA[nj] = mfma16(kf[nj][1], qfA[1], stA[nj]);
      }
    }
    // ---- V tile loads (kf dead; latency hides under softmax) ----
    bf16x8 vf[4][2];
    const short* vp0 = Vb + (size_t)lr * S_LEN + kv0 + lk;
#pragma unroll
    for (int nd = 0; nd < 4; ++nd) {
      vf[nd][0] = *(const bf16x8*)(vp0 + (size_t)nd * 16 * S_LEN);
      vf[nd][1] = *(const bf16x8*)(vp0 + (size_t)nd * 16 * S_LEN + 32);
    }
    // ---- causal masks (only on each strip's last tile) ----
    if (doA && it == ntA - 1) {
#pragma unroll
      for (int nj = 0; nj < 4; ++nj)
#pragma unroll
        for (int r = 0; r < 4; ++r)
          if (kv0 + nj * 16 + (g << 2) + r > qaA) stA[nj][r] = -1e30f;
    }
    if (it == ntB - 1) {
#pragma unroll
      for (int nj = 0; nj < 4; ++nj)
#pragma unroll
        for (int r = 0; r < 4; ++r)
          if (kv0 + nj * 16 + (g << 2) + r > qaB) stB[nj][r] = -1e30f;
    }
    // ---- softmax + PV ----
    if (doA) softmax_pv(stA, otA, mA, lA, vf);
    softmax_pv(stB, otB, mB, lB, vf);
  }

  attn_epilogue(otA, lA, b, h, qaA, g, AO);
  attn_epilogue(otB, lB, b, h, qaB, g, AO);
}

extern "C" void kernel_launch(void* const* d_in, const int* in_sizes, int n_in,
                              void* d_out, int out_size, void* d_ws, size_t ws_size,
                              hipStream_t stream) {
  const float* query = (const float*)d_in[0];
  const float* key   = (const float*)d_in[1];
  const float* value = (const float*)d_in[2];
  const float* w_q = (const float*)d_in[4];
  const float* w_k = (const float*)d_in[5];
  const float* w_v = (const float*)d_in[6];
  const float* w_o = (const float*)d_in[7];

  const size_t QKV = (size_t)BATCH * NH * S_LEN * DHEAD;  // 8388608
  short* Qp = (short*)d_ws;
  short* Kp = Qp + QKV;
  short* Vt = Kp + QKV;
  short* AO = Vt + QKV;
  short* Wto = Qp;                   // w_o^T bf16, reuses Qp after attn
  short* qb  = (short*)d_out;        // d_out as staging until final GEMM
  short* Wtq = qb + QKV;
  short* Wtk = Wtq + (size_t)DMODEL * DMODEL;
  short* Wtv = Wtk + (size_t)DMODEL * DMODEL;

  dim3 blk(256);
  dim3 gg(DMODEL / 128, (BATCH * S_LEN) / 128);   // (8, 64)
  const float qscale = 0.125f * 1.4426950408889634f;  // 1/sqrt(64) * log2(e)

  transpose_w3<<<dim3(16, 16, 3), blk, 0, stream>>>(w_q, w_k, w_v, Wtq, Wtk, Wtv);
  cvt_bf16<<<4096, blk, 0, stream>>>(query, qb);
  gemm128<0><<<gg, blk, 0, stream>>>(qb, Wtq, Qp, qscale);
  cvt_bf16<<<4096, blk, 0, stream>>>(key, qb);
  gemm128<0><<<gg, blk, 0, stream>>>(qb, Wtk, Kp, 1.0f);
  cvt_bf16<<<4096, blk, 0, stream>>>(value, qb);
  gemm128<1><<<gg, blk, 0, stream>>>(qb, Wtv, Vt, 1.0f);
  attn5<<<dim3(1024), blk, 0, stream>>>(Qp, Kp, Vt, AO);
  transpose_w1<<<dim3(16, 16), blk, 0, stream>>>(w_o, Wto);
  gemm128<2><<<gg, blk, 0, stream>>>(AO, Wto, d_out, 1.0f);
}

// Round 6
// 260.604 us; speedup vs baseline: 2.5897x; 1.4004x over previous
//
#include <hip/hip_runtime.h>
#include <hip/hip_bf16.h>

#define S_LEN 2048
#define NH 16
#define DHEAD 64
#define DMODEL 1024
#define BATCH 4

typedef __attribute__((ext_vector_type(4))) float f32x4;
typedef __attribute__((ext_vector_type(8))) short bf16x8;
typedef __attribute__((ext_vector_type(4))) short s16x4;
typedef __attribute__((ext_vector_type(4))) float fl4;
typedef __attribute__((ext_vector_type(4))) unsigned u32x4;

static __device__ __forceinline__ short f2bf(float f) {
  unsigned u = __builtin_bit_cast(unsigned, f);
  u += 0x7fffu + ((u >> 16) & 1u);   // RNE
  return (short)(u >> 16);
}
static __device__ __forceinline__ f32x4 mfma16(bf16x8 a, bf16x8 b, f32x4 c) {
  return __builtin_amdgcn_mfma_f32_16x16x32_bf16(a, b, c, 0, 0, 0);
}
static __device__ __forceinline__ void gl_lds16(const short* g, short* l) {
  __builtin_amdgcn_global_load_lds(
      (const __attribute__((address_space(1))) unsigned*)g,
      (__attribute__((address_space(3))) unsigned*)l, 16, 0, 0);
}
static __device__ __forceinline__ unsigned cvt_pk_bf16(float lo, float hi) {
  unsigned r;
  asm("v_cvt_pk_bf16_f32 %0, %1, %2" : "=v"(r) : "v"(lo), "v"(hi));
  return r;
}

// f32 -> bf16 elementwise, 8 elems/thread
__global__ __launch_bounds__(256) void cvt_bf16(const float* __restrict__ src,
                                                short* __restrict__ dst) {
  const size_t i = ((size_t)blockIdx.x * 256 + threadIdx.x) * 8;
  fl4 a = *(const fl4*)(src + i);
  fl4 b = *(const fl4*)(src + i + 4);
  bf16x8 o;
  o[0] = f2bf(a.x); o[1] = f2bf(a.y); o[2] = f2bf(a.z); o[3] = f2bf(a.w);
  o[4] = f2bf(b.x); o[5] = f2bf(b.y); o[6] = f2bf(b.z); o[7] = f2bf(b.w);
  *(bf16x8*)(dst + i) = o;
}

// W f32 [1024k][1024n] -> bf16 transposed [1024n][1024k], 64x64 tiles
__global__ __launch_bounds__(256) void transpose_w3(
    const float* __restrict__ w0, const float* __restrict__ w1,
    const float* __restrict__ w2, short* __restrict__ o0,
    short* __restrict__ o1, short* __restrict__ o2) {
  const float* W = blockIdx.z == 0 ? w0 : blockIdx.z == 1 ? w1 : w2;
  short* O = blockIdx.z == 0 ? o0 : blockIdx.z == 1 ? o1 : o2;
  __shared__ __align__(16) short T[64][72];
  const int tid = threadIdx.x;
  const int k0 = blockIdx.y * 64, n0 = blockIdx.x * 64;
#pragma unroll
  for (int i = 0; i < 4; ++i) {
    int c = tid + i * 256;
    int kk = c >> 4, nn = (c & 15) << 2;
    fl4 v = *(const fl4*)(W + (size_t)(k0 + kk) * DMODEL + n0 + nn);
    T[nn + 0][kk] = f2bf(v.x);
    T[nn + 1][kk] = f2bf(v.y);
    T[nn + 2][kk] = f2bf(v.z);
    T[nn + 3][kk] = f2bf(v.w);
  }
  __syncthreads();
#pragma unroll
  for (int i = 0; i < 4; ++i) {
    int c = tid + i * 256;
    int nn = c >> 4, kk = (c & 15) << 2;
    *(s16x4*)(O + (size_t)(n0 + nn) * DMODEL + k0 + kk) = *(const s16x4*)&T[nn][kk];
  }
}

__global__ __launch_bounds__(256) void transpose_w1(
    const float* __restrict__ W, short* __restrict__ O) {
  __shared__ __align__(16) short T[64][72];
  const int tid = threadIdx.x;
  const int k0 = blockIdx.y * 64, n0 = blockIdx.x * 64;
#pragma unroll
  for (int i = 0; i < 4; ++i) {
    int c = tid + i * 256;
    int kk = c >> 4, nn = (c & 15) << 2;
    fl4 v = *(const fl4*)(W + (size_t)(k0 + kk) * DMODEL + n0 + nn);
    T[nn + 0][kk] = f2bf(v.x);
    T[nn + 1][kk] = f2bf(v.y);
    T[nn + 2][kk] = f2bf(v.z);
    T[nn + 3][kk] = f2bf(v.w);
  }
  __syncthreads();
#pragma unroll
  for (int i = 0; i < 4; ++i) {
    int c = tid + i * 256;
    int nn = c >> 4, kk = (c & 15) << 2;
    *(s16x4*)(O + (size_t)(n0 + nn) * DMODEL + k0 + kk) = *(const s16x4*)&T[nn][kk];
  }
}

// C[8192x1024] = A(bf16)[8192][1024] * Bt(bf16)[n][k]
// OUT_MODE 0: bf16 [B,H,S,64]*scale; 1: bf16 [B,H,64,S]; 2: f32 [8192][1024]
template <int OUT_MODE>
__global__ __launch_bounds__(256) void gemm128(
    const short* __restrict__ A, const short* __restrict__ Bt,
    void* __restrict__ OutP, float scale) {
  __shared__ __align__(16) short As[128 * 32];
  __shared__ __align__(16) short Bs[128 * 32];
  const int tid = threadIdx.x, lane = tid & 63, wid = tid >> 6;
  const int m0 = blockIdx.y * 128, n0 = blockIdx.x * 128;
  const int wm = (wid >> 1) * 64, wn = (wid & 1) * 64;
  const int lr = lane & 15, g = lane >> 4, lk = g << 3;

  f32x4 acc[4][4] = {};

  const int srow = wid * 32 + (lane >> 2);
  const int scol = (lane & 3) * 8;
  short* ldsA = As + wid * 1024 + lane * 8;
  short* ldsB = Bs + wid * 1024 + lane * 8;

  for (int k0 = 0; k0 < DMODEL; k0 += 32) {
    __syncthreads();
    {
      const short* ga = A + (size_t)(m0 + srow) * DMODEL + k0 + scol;
      gl_lds16(ga, ldsA);
      gl_lds16(ga + (size_t)16 * DMODEL, ldsA + 512);
      const short* gb = Bt + (size_t)(n0 + srow) * DMODEL + k0 + scol;
      gl_lds16(gb, ldsB);
      gl_lds16(gb + (size_t)16 * DMODEL, ldsB + 512);
    }
    __syncthreads();

    bf16x8 af[4], bfr[4];
#pragma unroll
    for (int t = 0; t < 4; ++t) {
      af[t] = *(const bf16x8*)&As[(wm + t * 16 + lr) * 32 + lk];
      bfr[t] = *(const bf16x8*)&Bs[(wn + t * 16 + lr) * 32 + lk];
    }
#pragma unroll
    for (int mi = 0; mi < 4; ++mi)
#pragma unroll
      for (int ni = 0; ni < 4; ++ni)
        acc[mi][ni] = mfma16(af[mi], bfr[ni], acc[mi][ni]);
  }

  if (OUT_MODE == 0) {
    short* Out = (short*)OutP;
#pragma unroll
    for (int mi = 0; mi < 4; ++mi)
#pragma unroll
      for (int ni = 0; ni < 4; ++ni) {
        const int n = n0 + wn + ni * 16 + lr;
        const int h = n >> 6, d = n & 63;
#pragma unroll
        for (int r = 0; r < 4; ++r) {
          const int m = m0 + wm + mi * 16 + g * 4 + r;
          const int b = m >> 11, s = m & (S_LEN - 1);
          Out[(((size_t)b * NH + h) * S_LEN + s) * DHEAD + d] =
              f2bf(acc[mi][ni][r] * scale);
        }
      }
  } else if (OUT_MODE == 1) {
    short* Out = (short*)OutP;
#pragma unroll
    for (int mi = 0; mi < 4; ++mi) {
      const int mb = m0 + wm + mi * 16 + g * 4;
      const int b = mb >> 11, s = mb & (S_LEN - 1);
#pragma unroll
      for (int ni = 0; ni < 4; ++ni) {
        const int n = n0 + wn + ni * 16 + lr;
        const int h = n >> 6, d = n & 63;
        s16x4 pv;
        pv.x = f2bf(acc[mi][ni][0]);
        pv.y = f2bf(acc[mi][ni][1]);
        pv.z = f2bf(acc[mi][ni][2]);
        pv.w = f2bf(acc[mi][ni][3]);
        *(s16x4*)(Out + (((size_t)b * NH + h) * DHEAD + d) * S_LEN + s) = pv;
      }
    }
  } else {
    float* Out = (float*)OutP;
#pragma unroll
    for (int mi = 0; mi < 4; ++mi)
#pragma unroll
      for (int ni = 0; ni < 4; ++ni) {
        const int n = n0 + wn + ni * 16 + lr;
#pragma unroll
        for (int r = 0; r < 4; ++r) {
          const int m = m0 + wm + mi * 16 + g * 4 + r;
          Out[(size_t)m * DMODEL + n] = acc[mi][ni][r];
        }
      }
  }
}

// ---- softmax: st (P^T C-layout) -> running m/l update -> pf (B-frag of P^T) ----
static __device__ __forceinline__ void softmax_pf(
    f32x4 (&st)[4], f32x4 (&ot)[4], float& m, float& lsum,
    bf16x8& pf0, bf16x8& pf1) {
  float mx = fmaxf(fmaxf(fmaxf(st[0][0], st[0][1]), fmaxf(st[0][2], st[0][3])),
                   fmaxf(fmaxf(st[1][0], st[1][1]), fmaxf(st[1][2], st[1][3])));
  mx = fmaxf(mx, fmaxf(fmaxf(fmaxf(st[2][0], st[2][1]), fmaxf(st[2][2], st[2][3])),
                       fmaxf(fmaxf(st[3][0], st[3][1]), fmaxf(st[3][2], st[3][3]))));
  mx = fmaxf(mx, __shfl_xor(mx, 16));
  mx = fmaxf(mx, __shfl_xor(mx, 32));
  if (__any(mx > m + 8.0f)) {          // defer-rescale (log2 domain)
    const float mnew = fmaxf(m, mx);
    const float corr = exp2f(m - mnew);
    m = mnew;
    lsum *= corr;
#pragma unroll
    for (int nd = 0; nd < 4; ++nd)
#pragma unroll
      for (int r = 0; r < 4; ++r) ot[nd][r] *= corr;
  }
  float ps = 0.f;
#pragma unroll
  for (int nj = 0; nj < 4; ++nj)
#pragma unroll
    for (int r = 0; r < 4; ++r) {
      const float p = exp2f(st[nj][r] - m);
      st[nj][r] = p;
      ps += p;
    }
  lsum += ps;                           // per-lane partial; reduced in epilogue
  // P^T -> B-frag via cvt_pk + permlane swaps (zero LDS)
  unsigned pw[2][4];
#pragma unroll
  for (int kc = 0; kc < 2; ++kc)
#pragma unroll
    for (int jj = 0; jj < 2; ++jj) {
      unsigned a = cvt_pk_bf16(st[2 * kc][2 * jj], st[2 * kc][2 * jj + 1]);
      unsigned bb = cvt_pk_bf16(st[2 * kc + 1][2 * jj], st[2 * kc + 1][2 * jj + 1]);
      asm("v_permlane32_swap_b32 %0, %1" : "+v"(a), "+v"(bb));
      asm("v_permlane16_swap_b32 %0, %1" : "+v"(a), "+v"(bb));
      pw[kc][jj] = a;
      pw[kc][jj + 2] = bb;
    }
  u32x4 w0 = {pw[0][0], pw[0][1], pw[0][2], pw[0][3]};
  u32x4 w1 = {pw[1][0], pw[1][1], pw[1][2], pw[1][3]};
  pf0 = __builtin_bit_cast(bf16x8, w0);
  pf1 = __builtin_bit_cast(bf16x8, w1);
}

static __device__ __forceinline__ void attn_epilogue(
    f32x4 (&ot)[4], float lsum, int b, int h, int qa, int g,
    short* __restrict__ AO) {
  lsum += __shfl_xor(lsum, 16);
  lsum += __shfl_xor(lsum, 32);
  const float inv = 1.f / lsum;
  short* dst = AO + ((size_t)b * S_LEN + qa) * DMODEL + h * DHEAD + (g << 2);
#pragma unroll
  for (int nd = 0; nd < 4; ++nd) {
    s16x4 pv;
    pv.x = f2bf(ot[nd][0] * inv);
    pv.y = f2bf(ot[nd][1] * inv);
    pv.z = f2bf(ot[nd][2] * inv);
    pv.w = f2bf(ot[nd][3] * inv);
    *(s16x4*)(dst + nd * 16) = pv;
  }
}

// causal flash attn: 4 waves/block on SAME bh share LDS-staged K/V tiles.
// global_load_lds + double-buffer + counted vmcnt + raw s_barrier.
// LDS XOR-swizzle (slot = col16 ^ (row&7)) applied via pre-swizzled global src.
// wave strip pair (t, 127-t), t = 4*bx + wid -> ntA = bx+1, NT = ntB = 32-bx
// IDENTICAL for all 4 waves (uniform barriers). Blocks launched heavy-first (LPT).
__global__ __launch_bounds__(256) void attn6(
    const short* __restrict__ Qp, const short* __restrict__ Kp,
    const short* __restrict__ VT, short* __restrict__ AO) {
  __shared__ __align__(16) short KV[2][8192];  // [buf][K:0..4095 | V:4096..8191]
  const int tid = threadIdx.x, lane = tid & 63, wid = tid >> 6;
  const int lr = lane & 15, g = lane >> 4;
  const int id = blockIdx.x;
  const int xcd = id & 7;                      // XCD-local bh
  const int bh = xcd * 8 + ((id >> 3) & 7);
  const int bx = id >> 6;                      // 0..15, ascending = heavy first
  const int t = bx * 4 + wid;                  // 0..63
  const short* Qb = Qp + (size_t)bh * S_LEN * DHEAD;
  const short* Kb = Kp + (size_t)bh * S_LEN * DHEAD;
  const short* Vb = VT + (size_t)bh * DHEAD * S_LEN;
  const int b = bh >> 4, h = bh & 15;

  const int ntA = bx + 1, NT = 32 - bx;        // uniform across block
  const int q0A = t << 4, q0B = (127 - t) << 4;
  const int qaA = q0A + lr, qaB = q0B + lr;

  // staging source offsets (pre-swizzled): chunk c=tid -> row=c>>3, slot=c&7,
  // global col16 = slot ^ (row&7)
  const int row1 = tid >> 3;
  const int col1 = (tid & 7) ^ (row1 & 7);
  const int kOff1 = row1 * DHEAD + col1 * 8;   // shorts
  const int vOff1 = row1 * S_LEN + col1 * 8;

#define STAGE6(bufi, kvv) do {                                      \
    const short* ks_ = Kb + (size_t)(kvv) * DHEAD + kOff1;          \
    gl_lds16(ks_,               &KV[bufi][0] + tid * 8);            \
    gl_lds16(ks_ + 32 * DHEAD,  &KV[bufi][2048] + tid * 8);         \
    const short* vs_ = Vb + (kvv) + vOff1;                          \
    gl_lds16(vs_,               &KV[bufi][4096] + tid * 8);         \
    gl_lds16(vs_ + 32 * S_LEN,  &KV[bufi][6144] + tid * 8);         \
  } while (0)

  // fragment read bases (swizzled): row lr, slot = g ^ (lr&7); +64B = slot^4
  const int slot0 = g ^ (lr & 7);
  const int fOff0 = lr * 64 + slot0 * 8;          // shorts
  const int fOff1 = lr * 64 + (slot0 ^ 4) * 8;

  bf16x8 qfA[2], qfB[2];
  qfA[0] = *(const bf16x8*)(Qb + (size_t)qaA * DHEAD + (g << 3));
  qfA[1] = *(const bf16x8*)(Qb + (size_t)qaA * DHEAD + 32 + (g << 3));
  qfB[0] = *(const bf16x8*)(Qb + (size_t)qaB * DHEAD + (g << 3));
  qfB[1] = *(const bf16x8*)(Qb + (size_t)qaB * DHEAD + 32 + (g << 3));

  f32x4 otA[4] = {}, otB[4] = {};
  float mA = -1e30f, lA = 0.f, mB = -1e30f, lB = 0.f;

  STAGE6(0, 0);                                  // prologue: tile 0 -> buf 0

  for (int it = 0; it < NT; ++it) {
    const int kv0 = it << 6;
    const int cb = it & 1;
    if (it + 1 < NT) {
      STAGE6(cb ^ 1, kv0 + 64);
      asm volatile("s_waitcnt vmcnt(4)" ::: "memory");   // my prev 4 stages done
    } else {
      asm volatile("s_waitcnt vmcnt(0)" ::: "memory");
    }
    __builtin_amdgcn_s_barrier();                // everyone's stage of buf cb done

    const short* kb = &KV[cb][0];
    const short* vb = &KV[cb][4096];
    const bool doA = (it < ntA);

    // ---- QK^T (K frags JIT from LDS) ----
    f32x4 stA[4] = {}, stB[4] = {};
#pragma unroll
    for (int nj = 0; nj < 4; ++nj) {
      bf16x8 k0 = *(const bf16x8*)(kb + fOff0 + nj * 1024);
      bf16x8 k1 = *(const bf16x8*)(kb + fOff1 + nj * 1024);
      stB[nj] = mfma16(k0, qfB[0], stB[nj]);
      stB[nj] = mfma16(k1, qfB[1], stB[nj]);
      if (doA) {
        stA[nj] = mfma16(k0, qfA[0], stA[nj]);
        stA[nj] = mfma16(k1, qfA[1], stA[nj]);
      }
    }
    // ---- causal masks (each strip's diagonal tile only) ----
    if (doA && it == ntA - 1) {
#pragma unroll
      for (int nj = 0; nj < 4; ++nj)
#pragma unroll
        for (int r = 0; r < 4; ++r)
          if (kv0 + nj * 16 + (g << 2) + r > qaA) stA[nj][r] = -1e30f;
    }
    if (it == NT - 1) {
#pragma unroll
      for (int nj = 0; nj < 4; ++nj)
#pragma unroll
        for (int r = 0; r < 4; ++r)
          if (kv0 + nj * 16 + (g << 2) + r > qaB) stB[nj][r] = -1e30f;
    }
    // ---- softmax ----
    bf16x8 pfA0, pfA1, pfB0, pfB1;
    if (doA) softmax_pf(stA, otA, mA, lA, pfA0, pfA1);
    softmax_pf(stB, otB, mB, lB, pfB0, pfB1);
    // ---- PV (V frags JIT from LDS) ----
#pragma unroll
    for (int nd = 0; nd < 4; ++nd) {
      bf16x8 v0 = *(const bf16x8*)(vb + fOff0 + nd * 1024);
      bf16x8 v1 = *(const bf16x8*)(vb + fOff1 + nd * 1024);
      if (doA) {
        otA[nd] = mfma16(v0, pfA0, otA[nd]);
        otA[nd] = mfma16(v1, pfA1, otA[nd]);
      }
      otB[nd] = mfma16(v0, pfB0, otB[nd]);
      otB[nd] = mfma16(v1, pfB1, otB[nd]);
    }
    __builtin_amdgcn_s_barrier();                // reads of buf cb complete
  }
#undef STAGE6

  attn_epilogue(otA, lA, b, h, qaA, g, AO);
  attn_epilogue(otB, lB, b, h, qaB, g, AO);
}

extern "C" void kernel_launch(void* const* d_in, const int* in_sizes, int n_in,
                              void* d_out, int out_size, void* d_ws, size_t ws_size,
                              hipStream_t stream) {
  const float* query = (const float*)d_in[0];
  const float* key   = (const float*)d_in[1];
  const float* value = (const float*)d_in[2];
  const float* w_q = (const float*)d_in[4];
  const float* w_k = (const float*)d_in[5];
  const float* w_v = (const float*)d_in[6];
  const float* w_o = (const float*)d_in[7];

  const size_t QKV = (size_t)BATCH * NH * S_LEN * DHEAD;  // 8388608
  short* Qp = (short*)d_ws;
  short* Kp = Qp + QKV;
  short* Vt = Kp + QKV;
  short* AO = Vt + QKV;
  short* Wto = Qp;                   // w_o^T bf16, reuses Qp after attn
  short* qb  = (short*)d_out;        // d_out as staging until final GEMM
  short* Wtq = qb + QKV;
  short* Wtk = Wtq + (size_t)DMODEL * DMODEL;
  short* Wtv = Wtk + (size_t)DMODEL * DMODEL;

  dim3 blk(256);
  dim3 gg(DMODEL / 128, (BATCH * S_LEN) / 128);   // (8, 64)
  const float qscale = 0.125f * 1.4426950408889634f;  // 1/sqrt(64) * log2(e)

  transpose_w3<<<dim3(16, 16, 3), blk, 0, stream>>>(w_q, w_k, w_v, Wtq, Wtk, Wtv);
  cvt_bf16<<<4096, blk, 0, stream>>>(query, qb);
  gemm128<0><<<gg, blk, 0, stream>>>(qb, Wtq, Qp, qscale);
  cvt_bf16<<<4096, blk, 0, stream>>>(key, qb);
  gemm128<0><<<gg, blk, 0, stream>>>(qb, Wtk, Kp, 1.0f);
  cvt_bf16<<<4096, blk, 0, stream>>>(value, qb);
  gemm128<1><<<gg, blk, 0, stream>>>(qb, Wtv, Vt, 1.0f);
  attn6<<<dim3(1024), blk, 0, stream>>>(Qp, Kp, Vt, AO);
  transpose_w1<<<dim3(16, 16), blk, 0, stream>>>(w_o, Wto);
  gemm128<2><<<gg, blk, 0, stream>>>(AO, Wto, d_out, 1.0f);
}

// Round 7
// 260.472 us; speedup vs baseline: 2.5910x; 1.0005x over previous
//
#include <hip/hip_runtime.h>
#include <hip/hip_bf16.h>

#define S_LEN 2048
#define NH 16
#define DHEAD 64
#define DMODEL 1024
#define BATCH 4

typedef __attribute__((ext_vector_type(4))) float f32x4;
typedef __attribute__((ext_vector_type(8))) short bf16x8;
typedef __attribute__((ext_vector_type(4))) short s16x4;
typedef __attribute__((ext_vector_type(4))) float fl4;
typedef __attribute__((ext_vector_type(4))) unsigned u32x4;

static __device__ __forceinline__ short f2bf(float f) {
  unsigned u = __builtin_bit_cast(unsigned, f);
  u += 0x7fffu + ((u >> 16) & 1u);   // RNE
  return (short)(u >> 16);
}
static __device__ __forceinline__ f32x4 mfma16(bf16x8 a, bf16x8 b, f32x4 c) {
  return __builtin_amdgcn_mfma_f32_16x16x32_bf16(a, b, c, 0, 0, 0);
}
static __device__ __forceinline__ void gl_lds16(const short* g, short* l) {
  __builtin_amdgcn_global_load_lds(
      (const __attribute__((address_space(1))) unsigned*)g,
      (__attribute__((address_space(3))) unsigned*)l, 16, 0, 0);
}
static __device__ __forceinline__ unsigned cvt_pk_bf16(float lo, float hi) {
  unsigned r;
  asm("v_cvt_pk_bf16_f32 %0, %1, %2" : "=v"(r) : "v"(lo), "v"(hi));
  return r;
}
static __device__ __forceinline__ float max3f(float a, float b, float c) {
  float r;
  asm("v_max3_f32 %0, %1, %2, %3" : "=v"(r) : "v"(a), "v"(b), "v"(c));
  return r;
}

// f32 -> bf16 elementwise, 8 elems/thread
__global__ __launch_bounds__(256) void cvt_bf16(const float* __restrict__ src,
                                                short* __restrict__ dst) {
  const size_t i = ((size_t)blockIdx.x * 256 + threadIdx.x) * 8;
  fl4 a = *(const fl4*)(src + i);
  fl4 b = *(const fl4*)(src + i + 4);
  bf16x8 o;
  o[0] = f2bf(a.x); o[1] = f2bf(a.y); o[2] = f2bf(a.z); o[3] = f2bf(a.w);
  o[4] = f2bf(b.x); o[5] = f2bf(b.y); o[6] = f2bf(b.z); o[7] = f2bf(b.w);
  *(bf16x8*)(dst + i) = o;
}

// W f32 [1024k][1024n] -> bf16 transposed [1024n][1024k], 64x64 tiles
__global__ __launch_bounds__(256) void transpose_w3(
    const float* __restrict__ w0, const float* __restrict__ w1,
    const float* __restrict__ w2, short* __restrict__ o0,
    short* __restrict__ o1, short* __restrict__ o2) {
  const float* W = blockIdx.z == 0 ? w0 : blockIdx.z == 1 ? w1 : w2;
  short* O = blockIdx.z == 0 ? o0 : blockIdx.z == 1 ? o1 : o2;
  __shared__ __align__(16) short T[64][72];
  const int tid = threadIdx.x;
  const int k0 = blockIdx.y * 64, n0 = blockIdx.x * 64;
#pragma unroll
  for (int i = 0; i < 4; ++i) {
    int c = tid + i * 256;
    int kk = c >> 4, nn = (c & 15) << 2;
    fl4 v = *(const fl4*)(W + (size_t)(k0 + kk) * DMODEL + n0 + nn);
    T[nn + 0][kk] = f2bf(v.x);
    T[nn + 1][kk] = f2bf(v.y);
    T[nn + 2][kk] = f2bf(v.z);
    T[nn + 3][kk] = f2bf(v.w);
  }
  __syncthreads();
#pragma unroll
  for (int i = 0; i < 4; ++i) {
    int c = tid + i * 256;
    int nn = c >> 4, kk = (c & 15) << 2;
    *(s16x4*)(O + (size_t)(n0 + nn) * DMODEL + k0 + kk) = *(const s16x4*)&T[nn][kk];
  }
}

__global__ __launch_bounds__(256) void transpose_w1(
    const float* __restrict__ W, short* __restrict__ O) {
  __shared__ __align__(16) short T[64][72];
  const int tid = threadIdx.x;
  const int k0 = blockIdx.y * 64, n0 = blockIdx.x * 64;
#pragma unroll
  for (int i = 0; i < 4; ++i) {
    int c = tid + i * 256;
    int kk = c >> 4, nn = (c & 15) << 2;
    fl4 v = *(const fl4*)(W + (size_t)(k0 + kk) * DMODEL + n0 + nn);
    T[nn + 0][kk] = f2bf(v.x);
    T[nn + 1][kk] = f2bf(v.y);
    T[nn + 2][kk] = f2bf(v.z);
    T[nn + 3][kk] = f2bf(v.w);
  }
  __syncthreads();
#pragma unroll
  for (int i = 0; i < 4; ++i) {
    int c = tid + i * 256;
    int nn = c >> 4, kk = (c & 15) << 2;
    *(s16x4*)(O + (size_t)(n0 + nn) * DMODEL + k0 + kk) = *(const s16x4*)&T[nn][kk];
  }
}

// C[8192x1024] = A(bf16)[8192][1024] * Bt(bf16)[n][k]
// OUT_MODE 0: bf16 [B,H,S,64]*scale; 1: bf16 [B,H,64,S]; 2: f32 [8192][1024]
template <int OUT_MODE>
__global__ __launch_bounds__(256) void gemm128(
    const short* __restrict__ A, const short* __restrict__ Bt,
    void* __restrict__ OutP, float scale) {
  __shared__ __align__(16) short As[128 * 32];
  __shared__ __align__(16) short Bs[128 * 32];
  const int tid = threadIdx.x, lane = tid & 63, wid = tid >> 6;
  const int m0 = blockIdx.y * 128, n0 = blockIdx.x * 128;
  const int wm = (wid >> 1) * 64, wn = (wid & 1) * 64;
  const int lr = lane & 15, g = lane >> 4, lk = g << 3;

  f32x4 acc[4][4] = {};

  const int srow = wid * 32 + (lane >> 2);
  const int scol = (lane & 3) * 8;
  short* ldsA = As + wid * 1024 + lane * 8;
  short* ldsB = Bs + wid * 1024 + lane * 8;

  for (int k0 = 0; k0 < DMODEL; k0 += 32) {
    __syncthreads();
    {
      const short* ga = A + (size_t)(m0 + srow) * DMODEL + k0 + scol;
      gl_lds16(ga, ldsA);
      gl_lds16(ga + (size_t)16 * DMODEL, ldsA + 512);
      const short* gb = Bt + (size_t)(n0 + srow) * DMODEL + k0 + scol;
      gl_lds16(gb, ldsB);
      gl_lds16(gb + (size_t)16 * DMODEL, ldsB + 512);
    }
    __syncthreads();

    bf16x8 af[4], bfr[4];
#pragma unroll
    for (int t = 0; t < 4; ++t) {
      af[t] = *(const bf16x8*)&As[(wm + t * 16 + lr) * 32 + lk];
      bfr[t] = *(const bf16x8*)&Bs[(wn + t * 16 + lr) * 32 + lk];
    }
#pragma unroll
    for (int mi = 0; mi < 4; ++mi)
#pragma unroll
      for (int ni = 0; ni < 4; ++ni)
        acc[mi][ni] = mfma16(af[mi], bfr[ni], acc[mi][ni]);
  }

  if (OUT_MODE == 0) {
    short* Out = (short*)OutP;
#pragma unroll
    for (int mi = 0; mi < 4; ++mi)
#pragma unroll
      for (int ni = 0; ni < 4; ++ni) {
        const int n = n0 + wn + ni * 16 + lr;
        const int h = n >> 6, d = n & 63;
#pragma unroll
        for (int r = 0; r < 4; ++r) {
          const int m = m0 + wm + mi * 16 + g * 4 + r;
          const int b = m >> 11, s = m & (S_LEN - 1);
          Out[(((size_t)b * NH + h) * S_LEN + s) * DHEAD + d] =
              f2bf(acc[mi][ni][r] * scale);
        }
      }
  } else if (OUT_MODE == 1) {
    short* Out = (short*)OutP;
#pragma unroll
    for (int mi = 0; mi < 4; ++mi) {
      const int mb = m0 + wm + mi * 16 + g * 4;
      const int b = mb >> 11, s = mb & (S_LEN - 1);
#pragma unroll
      for (int ni = 0; ni < 4; ++ni) {
        const int n = n0 + wn + ni * 16 + lr;
        const int h = n >> 6, d = n & 63;
        s16x4 pv;
        pv.x = f2bf(acc[mi][ni][0]);
        pv.y = f2bf(acc[mi][ni][1]);
        pv.z = f2bf(acc[mi][ni][2]);
        pv.w = f2bf(acc[mi][ni][3]);
        *(s16x4*)(Out + (((size_t)b * NH + h) * DHEAD + d) * S_LEN + s) = pv;
      }
    }
  } else {
    float* Out = (float*)OutP;
#pragma unroll
    for (int mi = 0; mi < 4; ++mi)
#pragma unroll
      for (int ni = 0; ni < 4; ++ni) {
        const int n = n0 + wn + ni * 16 + lr;
#pragma unroll
        for (int r = 0; r < 4; ++r) {
          const int m = m0 + wm + mi * 16 + g * 4 + r;
          Out[(size_t)m * DMODEL + n] = acc[mi][ni][r];
        }
      }
  }
}

// ---- softmax: st (P^T C-layout) -> m update + P packed to B-frag.
// Sum is NOT reduced here: caller accumulates it via ones-MFMA into lacc.
static __device__ __forceinline__ void softmax_pf(
    f32x4 (&st)[4], f32x4 (&ot)[4], f32x4& lacc, float& m,
    bf16x8& pf0, bf16x8& pf1) {
  float mx = max3f(max3f(st[0][0], st[0][1], st[0][2]),
                   max3f(st[0][3], st[1][0], st[1][1]),
                   max3f(st[1][2], st[1][3], st[2][0]));
  mx = max3f(mx, max3f(st[2][1], st[2][2], st[2][3]),
             max3f(st[3][0], st[3][1], st[3][2]));
  mx = fmaxf(mx, st[3][3]);
  mx = fmaxf(mx, __shfl_xor(mx, 16));
  mx = fmaxf(mx, __shfl_xor(mx, 32));
  if (__any(mx > m + 8.0f)) {          // defer-rescale (log2 domain)
    const float mnew = fmaxf(m, mx);
    const float corr = exp2f(m - mnew);
    m = mnew;
#pragma unroll
    for (int r = 0; r < 4; ++r) lacc[r] *= corr;
#pragma unroll
    for (int nd = 0; nd < 4; ++nd)
#pragma unroll
      for (int r = 0; r < 4; ++r) ot[nd][r] *= corr;
  }
#pragma unroll
  for (int nj = 0; nj < 4; ++nj)
#pragma unroll
    for (int r = 0; r < 4; ++r)
      st[nj][r] = exp2f(st[nj][r] - m);
  // P^T -> B-frag via cvt_pk + permlane swaps (zero LDS)
  unsigned pw[2][4];
#pragma unroll
  for (int kc = 0; kc < 2; ++kc)
#pragma unroll
    for (int jj = 0; jj < 2; ++jj) {
      unsigned a = cvt_pk_bf16(st[2 * kc][2 * jj], st[2 * kc][2 * jj + 1]);
      unsigned bb = cvt_pk_bf16(st[2 * kc + 1][2 * jj], st[2 * kc + 1][2 * jj + 1]);
      asm("v_permlane32_swap_b32 %0, %1" : "+v"(a), "+v"(bb));
      asm("v_permlane16_swap_b32 %0, %1" : "+v"(a), "+v"(bb));
      pw[kc][jj] = a;
      pw[kc][jj + 2] = bb;
    }
  u32x4 w0 = {pw[0][0], pw[0][1], pw[0][2], pw[0][3]};
  u32x4 w1 = {pw[1][0], pw[1][1], pw[1][2], pw[1][3]};
  pf0 = __builtin_bit_cast(bf16x8, w0);
  pf1 = __builtin_bit_cast(bf16x8, w1);
}

static __device__ __forceinline__ void attn_epilogue(
    f32x4 (&ot)[4], float lsum, int b, int h, int qa, int g,
    short* __restrict__ AO) {
  const float inv = 1.f / lsum;        // lacc[0]: already full row-sum
  short* dst = AO + ((size_t)b * S_LEN + qa) * DMODEL + h * DHEAD + (g << 2);
#pragma unroll
  for (int nd = 0; nd < 4; ++nd) {
    s16x4 pv;
    pv.x = f2bf(ot[nd][0] * inv);
    pv.y = f2bf(ot[nd][1] * inv);
    pv.z = f2bf(ot[nd][2] * inv);
    pv.w = f2bf(ot[nd][3] * inv);
    *(s16x4*)(dst + nd * 16) = pv;
  }
}

// causal flash attn: 4 waves/block on SAME bh share LDS-staged K/V tiles.
// global_load_lds + double-buffer + counted vmcnt + raw s_barrier.
// LDS XOR-swizzle via pre-swizzled global src. Softmax sum via ones-MFMA.
__global__ __launch_bounds__(256) void attn7(
    const short* __restrict__ Qp, const short* __restrict__ Kp,
    const short* __restrict__ VT, short* __restrict__ AO) {
  __shared__ __align__(16) short KV[2][8192];  // [buf][K:0..4095 | V:4096..8191]
  const int tid = threadIdx.x, lane = tid & 63, wid = tid >> 6;
  const int lr = lane & 15, g = lane >> 4;
  const int id = blockIdx.x;
  const int xcd = id & 7;                      // XCD-local bh
  const int bh = xcd * 8 + ((id >> 3) & 7);
  const int bx = id >> 6;                      // 0..15, ascending = heavy first
  const int t = bx * 4 + wid;                  // 0..63
  const short* Qb = Qp + (size_t)bh * S_LEN * DHEAD;
  const short* Kb = Kp + (size_t)bh * S_LEN * DHEAD;
  const short* Vb = VT + (size_t)bh * DHEAD * S_LEN;
  const int b = bh >> 4, h = bh & 15;

  const int ntA = bx + 1, NT = 32 - bx;        // uniform across block
  const int q0A = t << 4, q0B = (127 - t) << 4;
  const int qaA = q0A + lr, qaB = q0B + lr;

  // staging source offsets (pre-swizzled): chunk c=tid -> row=c>>3, slot=c&7,
  // global col16 = slot ^ (row&7)
  const int row1 = tid >> 3;
  const int col1 = (tid & 7) ^ (row1 & 7);
  const int kOff1 = row1 * DHEAD + col1 * 8;   // shorts
  const int vOff1 = row1 * S_LEN + col1 * 8;

#define STAGE7(bufi, kvv) do {                                      \
    const short* ks_ = Kb + (size_t)(kvv) * DHEAD + kOff1;          \
    gl_lds16(ks_,               &KV[bufi][0] + tid * 8);            \
    gl_lds16(ks_ + 32 * DHEAD,  &KV[bufi][2048] + tid * 8);         \
    const short* vs_ = Vb + (kvv) + vOff1;                          \
    gl_lds16(vs_,               &KV[bufi][4096] + tid * 8);         \
    gl_lds16(vs_ + 32 * S_LEN,  &KV[bufi][6144] + tid * 8);         \
  } while (0)

  // fragment read bases (swizzled): row lr, slot = g ^ (lr&7); +64B = slot^4
  const int slot0 = g ^ (lr & 7);
  const int fOff0 = lr * 64 + slot0 * 8;          // shorts
  const int fOff1 = lr * 64 + (slot0 ^ 4) * 8;

  bf16x8 qfA[2], qfB[2];
  qfA[0] = *(const bf16x8*)(Qb + (size_t)qaA * DHEAD + (g << 3));
  qfA[1] = *(const bf16x8*)(Qb + (size_t)qaA * DHEAD + 32 + (g << 3));
  qfB[0] = *(const bf16x8*)(Qb + (size_t)qaB * DHEAD + (g << 3));
  qfB[1] = *(const bf16x8*)(Qb + (size_t)qaB * DHEAD + 32 + (g << 3));

  bf16x8 ones;
#pragma unroll
  for (int i = 0; i < 8; ++i) ones[i] = (short)0x3F80;  // bf16 1.0

  f32x4 otA[4] = {}, otB[4] = {};
  f32x4 laccA = {}, laccB = {};
  float mA = -1e30f, mB = -1e30f;

  STAGE7(0, 0);                                  // prologue: tile 0 -> buf 0

  for (int it = 0; it < NT; ++it) {
    const int kv0 = it << 6;
    const int cb = it & 1;
    if (it + 1 < NT) {
      STAGE7(cb ^ 1, kv0 + 64);
      asm volatile("s_waitcnt vmcnt(4)" ::: "memory");   // my prev 4 stages done
    } else {
      asm volatile("s_waitcnt vmcnt(0)" ::: "memory");
    }
    __builtin_amdgcn_s_barrier();                // everyone's stage of buf cb done

    const short* kb = &KV[cb][0];
    const short* vb = &KV[cb][4096];
    const bool doA = (it < ntA);

    // ---- QK^T (K frags JIT from LDS) ----
    f32x4 stA[4] = {}, stB[4] = {};
    __builtin_amdgcn_s_setprio(1);
#pragma unroll
    for (int nj = 0; nj < 4; ++nj) {
      bf16x8 k0 = *(const bf16x8*)(kb + fOff0 + nj * 1024);
      bf16x8 k1 = *(const bf16x8*)(kb + fOff1 + nj * 1024);
      stB[nj] = mfma16(k0, qfB[0], stB[nj]);
      stB[nj] = mfma16(k1, qfB[1], stB[nj]);
      if (doA) {
        stA[nj] = mfma16(k0, qfA[0], stA[nj]);
        stA[nj] = mfma16(k1, qfA[1], stA[nj]);
      }
    }
    __builtin_amdgcn_s_setprio(0);
    // ---- causal masks (each strip's diagonal tile only) ----
    if (doA && it == ntA - 1) {
#pragma unroll
      for (int nj = 0; nj < 4; ++nj)
#pragma unroll
        for (int r = 0; r < 4; ++r)
          if (kv0 + nj * 16 + (g << 2) + r > qaA) stA[nj][r] = -1e30f;
    }
    if (it == NT - 1) {
#pragma unroll
      for (int nj = 0; nj < 4; ++nj)
#pragma unroll
        for (int r = 0; r < 4; ++r)
          if (kv0 + nj * 16 + (g << 2) + r > qaB) stB[nj][r] = -1e30f;
    }
    // ---- softmax ----
    bf16x8 pfA0, pfA1, pfB0, pfB1;
    if (doA) softmax_pf(stA, otA, laccA, mA, pfA0, pfA1);
    softmax_pf(stB, otB, laccB, mB, pfB0, pfB1);
    // ---- PV + ones-MFMA row-sum (V frags JIT from LDS) ----
    __builtin_amdgcn_s_setprio(1);
    if (doA) {
      laccA = mfma16(ones, pfA0, laccA);
      laccA = mfma16(ones, pfA1, laccA);
    }
    laccB = mfma16(ones, pfB0, laccB);
    laccB = mfma16(ones, pfB1, laccB);
#pragma unroll
    for (int nd = 0; nd < 4; ++nd) {
      bf16x8 v0 = *(const bf16x8*)(vb + fOff0 + nd * 1024);
      bf16x8 v1 = *(const bf16x8*)(vb + fOff1 + nd * 1024);
      if (doA) {
        otA[nd] = mfma16(v0, pfA0, otA[nd]);
        otA[nd] = mfma16(v1, pfA1, otA[nd]);
      }
      otB[nd] = mfma16(v0, pfB0, otB[nd]);
      otB[nd] = mfma16(v1, pfB1, otB[nd]);
    }
    __builtin_amdgcn_s_setprio(0);
    __builtin_amdgcn_s_barrier();                // reads of buf cb complete
  }
#undef STAGE7

  attn_epilogue(otA, laccA[0], b, h, qaA, g, AO);
  attn_epilogue(otB, laccB[0], b, h, qaB, g, AO);
}

extern "C" void kernel_launch(void* const* d_in, const int* in_sizes, int n_in,
                              void* d_out, int out_size, void* d_ws, size_t ws_size,
                              hipStream_t stream) {
  const float* query = (const float*)d_in[0];
  const float* key   = (const float*)d_in[1];
  const float* value = (const float*)d_in[2];
  const float* w_q = (const float*)d_in[4];
  const float* w_k = (const float*)d_in[5];
  const float* w_v = (const float*)d_in[6];
  const float* w_o = (const float*)d_in[7];

  const size_t QKV = (size_t)BATCH * NH * S_LEN * DHEAD;  // 8388608
  short* Qp = (short*)d_ws;
  short* Kp = Qp + QKV;
  short* Vt = Kp + QKV;
  short* AO = Vt + QKV;
  short* Wto = Qp;                   // w_o^T bf16, reuses Qp after attn
  short* qb  = (short*)d_out;        // d_out as staging until final GEMM
  short* Wtq = qb + QKV;
  short* Wtk = Wtq + (size_t)DMODEL * DMODEL;
  short* Wtv = Wtk + (size_t)DMODEL * DMODEL;

  dim3 blk(256);
  dim3 gg(DMODEL / 128, (BATCH * S_LEN) / 128);   // (8, 64)
  const float qscale = 0.125f * 1.4426950408889634f;  // 1/sqrt(64) * log2(e)

  transpose_w3<<<dim3(16, 16, 3), blk, 0, stream>>>(w_q, w_k, w_v, Wtq, Wtk, Wtv);
  cvt_bf16<<<4096, blk, 0, stream>>>(query, qb);
  gemm128<0><<<gg, blk, 0, stream>>>(qb, Wtq, Qp, qscale);
  cvt_bf16<<<4096, blk, 0, stream>>>(key, qb);
  gemm128<0><<<gg, blk, 0, stream>>>(qb, Wtk, Kp, 1.0f);
  cvt_bf16<<<4096, blk, 0, stream>>>(value, qb);
  gemm128<1><<<gg, blk, 0, stream>>>(qb, Wtv, Vt, 1.0f);
  attn7<<<dim3(1024), blk, 0, stream>>>(Qp, Kp, Vt, AO);
  transpose_w1<<<dim3(16, 16), blk, 0, stream>>>(w_o, Wto);
  gemm128<2><<<gg, blk, 0, stream>>>(AO, Wto, d_out, 1.0f);
}